// Round 10
// baseline (22495.055 us; speedup 1.0000x reference)
//
#include <hip/hip_runtime.h>
#include <cstdint>

#define BATCH 4
#define NPTS  32768
#define SKP   512
#define M1    (SKP*4)   /* 2048 */
#define KA    32
#define KB    2
#define SPHN  128

// FPS distance: reference _fps uses sum((x-c)**2) = ((dx*dx+dy*dy)+dz*dz),
// pinned round-to-nearest, NO fma contraction (bitwise == numpy).
__device__ __forceinline__ float sqdist(float px, float py, float pz,
                                        float cx, float cy, float cz) {
  float dx = px - cx, dy = py - cy, dz = pz - cz;
  return __fadd_rn(__fadd_rn(__fmul_rn(dx, dx), __fmul_rn(dy, dy)),
                   __fmul_rn(dz, dz));
}
// sklnz distance: reference _pairwise_sqdist uses c2 + p2 - 2*cp (Gram form):
// d2 = (q2 + p2) - 2*cp, cp = ((qx*px + qy*py) + qz*pz). Pinned, no fma.
__device__ __forceinline__ float d2gram(float px, float py, float pz,
                                        float qx, float qy, float qz, float q2) {
  float p2 = __fadd_rn(__fadd_rn(__fmul_rn(px, px), __fmul_rn(py, py)),
                       __fmul_rn(pz, pz));
  float cp = __fadd_rn(__fadd_rn(__fmul_rn(qx, px), __fmul_rn(qy, py)),
                       __fmul_rn(qz, pz));
  return __fsub_rn(__fadd_rn(q2, p2), __fadd_rn(cp, cp));
}

// ---------------------------------------------------------------------------
// Stage-1 FPS: one 1024-thread block per batch. x,y in VGPRs (64), z in LDS
// (128KB), dist[] in 32 VGPRs -> ~112 VGPRs needed.
// Attribute strategy (R7/R8 post-mortem): __launch_bounds__ only sets a MIN
// occupancy (VGPR upper bound), the allocator still targeted 8 waves/EU at
// 64 VGPRs and spilled 64 floats/thread (R6-R9: 8.3us/iter scratch/stream
// latency chains, one-CU streaming caps at ~30GB/s). The knob that LOWERS
// the allocator's occupancy target is the MAX in amdgpu_waves_per_eu, which
// must not be overridden by __launch_bounds__' own emitted attributes ->
// declare both amdgpu attributes directly, no __launch_bounds__.
// 4 waves/EU = exactly one 1024-thread block (LDS limits to 1 block/CU
// anyway) -> VGPR budget 128.
// One barrier/iter. Tie-break: smaller index (jnp.argmax).
// ---------------------------------------------------------------------------
__attribute__((amdgpu_flat_work_group_size(1024, 1024), amdgpu_waves_per_eu(4, 4)))
__global__ void fps1_kernel(const float* __restrict__ xyz, int* __restrict__ ids)
{
  int b = blockIdx.x;
  const float* X = xyz + (size_t)b * NPTS * 3;
  ids += (size_t)b * M1;
  int tid = threadIdx.x, lane = tid & 63, wave = tid >> 6;

  __shared__ float zsh[NPTS];          // 131072 B
  __shared__ float s_v[2][16];
  __shared__ int   s_i[2][16];

  float xr[32], yr[32], dist[32];
#pragma unroll
  for (int j = 0; j < 32; ++j) {
    int p = tid + 1024 * j;
    xr[j] = X[3*p];
    yr[j] = X[3*p+1];
    zsh[p] = X[3*p+2];
    dist[j] = 1e10f;
  }
  __syncthreads();

  if (tid == 0) ids[0] = 0;
  float cx = X[0], cy = X[1], cz = X[2];

  for (int it = 1; it < M1; ++it) {
    float best = -1.f; int besti = 0;
#pragma unroll
    for (int j = 0; j < 32; ++j) {
      int p = tid + 1024 * j;
      float d = sqdist(xr[j], yr[j], zsh[p], cx, cy, cz);
      d = fminf(dist[j], d);
      dist[j] = d;
      bool gt = d > best;
      best  = gt ? d : best;
      besti = gt ? p : besti;
    }
#pragma unroll
    for (int off = 32; off > 0; off >>= 1) {
      float ov = __shfl_xor(best, off);
      int   oi = __shfl_xor(besti, off);
      if (ov > best || (ov == best && oi < besti)) { best = ov; besti = oi; }
    }
    int par = it & 1;
    if (lane == 0) { s_v[par][wave] = best; s_i[par][wave] = besti; }
    __syncthreads();
    float v = -1.f; int i = 0x7fffffff;
    if (lane < 16) { v = s_v[par][lane]; i = s_i[par][lane]; }
#pragma unroll
    for (int off = 8; off > 0; off >>= 1) {
      float ov = __shfl_xor(v, off);
      int   oi = __shfl_xor(i, off);
      if (ov > v || (ov == v && oi < i)) { v = ov; i = oi; }
    }
    i = __shfl(i, 0);
    if (tid == 0) ids[it] = i;
    cx = X[3*i]; cy = X[3*i+1]; cz = zsh[i];
  }
}

// ---------------------------------------------------------------------------
// Stage-2 FPS on the 2048-pt intermediate skeleton. Points staged once into
// LDS (32KB) -> per-iter reads are ds_read_b128 instead of global-latency
// chains.
// ---------------------------------------------------------------------------
__global__ __launch_bounds__(256)
void fps2_kernel(const float4* __restrict__ pts, int* __restrict__ ids)
{
  const int PTS = 8, BLOCK = 256, NW = 4;
  int b = blockIdx.x;
  pts += (size_t)b * M1;
  ids += (size_t)b * SKP;
  int tid = threadIdx.x, lane = tid & 63, wave = tid >> 6;

  __shared__ float4 pl[M1];            // 32768 B
  __shared__ float s_v[2][NW];
  __shared__ int   s_i[2][NW];

  float dist[PTS];
#pragma unroll
  for (int j = 0; j < PTS; ++j) {
    int p = tid + BLOCK * j;
    pl[p] = pts[p];
    dist[j] = 1e10f;
  }
  __syncthreads();

  if (tid == 0) ids[0] = 0;
  float4 piv = pl[0];
  float cx = piv.x, cy = piv.y, cz = piv.z;

  for (int it = 1; it < SKP; ++it) {
    float best = -1.f; int besti = 0;
#pragma unroll
    for (int j = 0; j < PTS; ++j) {
      int p = tid + BLOCK * j;
      float4 f = pl[p];
      float d = sqdist(f.x, f.y, f.z, cx, cy, cz);
      d = fminf(dist[j], d);
      dist[j] = d;
      bool gt = d > best;
      best  = gt ? d : best;
      besti = gt ? p : besti;
    }
#pragma unroll
    for (int off = 32; off > 0; off >>= 1) {
      float ov = __shfl_xor(best, off);
      int   oi = __shfl_xor(besti, off);
      if (ov > best || (ov == best && oi < besti)) { best = ov; besti = oi; }
    }
    int par = it & 1;
    if (lane == 0) { s_v[par][wave] = best; s_i[par][wave] = besti; }
    __syncthreads();
    float v = -1.f; int i = 0x7fffffff;
    if (lane < NW) { v = s_v[par][lane]; i = s_i[par][lane]; }
#pragma unroll
    for (int off = NW >> 1; off > 0; off >>= 1) {
      float ov = __shfl_xor(v, off);
      int   oi = __shfl_xor(i, off);
      if (ov > v || (ov == v && oi < i)) { v = ov; i = oi; }
    }
    i = __shfl(i, 0);
    if (tid == 0) ids[it] = i;
    float4 pv = pl[i];
    cx = pv.x; cy = pv.y; cz = pv.z;
  }
}

// ---------------------------------------------------------------------------
// Skeletonization: wave per query. Distances via the reference's GRAM form.
// Branch-free sorted top-K per lane, LDS heads-merge -> exact K-th smallest
// t (with multiplicity), then exact-K selection: accumulate d < t strictly,
// fill need = K - count(d<t) slots with d == t in ascending index order
// (lax.top_k tie semantics). S3=true: pts is f32 xyz triplets; else float4.
// ---------------------------------------------------------------------------
template<int K, int N, bool S3>
__global__ __launch_bounds__(256)
void sklnz_kernel(const float4* __restrict__ queries,
                  const void*   __restrict__ ptsv,
                  float4* __restrict__ outc,
                  float*  __restrict__ outr,
                  int M)
{
  const int CH = N / 64;
  int wave = threadIdx.x >> 6, lane = threadIdx.x & 63;
  int qid = blockIdx.x * 4 + wave;
  int b = qid / M;
  const float*  P3 = (const float*)ptsv + (size_t)b * N * 3;
  const float4* P4 = (const float4*)ptsv + (size_t)b * N;
  float4 q = queries[qid];
  float q2 = __fadd_rn(__fadd_rn(__fmul_rn(q.x, q.x), __fmul_rn(q.y, q.y)),
                       __fmul_rn(q.z, q.z));

  float a[K];
#pragma unroll
  for (int s = 0; s < K; ++s) a[s] = 3.0e38f;

  for (int j = 0; j < CH; ++j) {
    int p = lane + 64 * j;
    float px, py, pz;
    if (S3) { px = P3[3*p]; py = P3[3*p+1]; pz = P3[3*p+2]; }
    else    { float4 f = P4[p]; px = f.x; py = f.y; pz = f.z; }
    float d = d2gram(px, py, pz, q.x, q.y, q.z, q2);
#pragma unroll
    for (int s = K - 1; s > 0; --s) a[s] = fminf(a[s], fmaxf(a[s-1], d));
    a[0] = fminf(a[0], d);
  }

  // merge 64 sorted lists -> t = K-th smallest of the union (with multiplicity)
  __shared__ float heads[4][64][K + 1];
#pragma unroll
  for (int s = 0; s < K; ++s) heads[wave][lane][s] = a[s];
  heads[wave][lane][K] = 3.1e38f;
  int h = 0; float t = 0.f;
  for (int r = 0; r < K; ++r) {
    float mv = heads[wave][lane][h];
    int   ml = lane;
#pragma unroll
    for (int off = 32; off > 0; off >>= 1) {
      float ov = __shfl_xor(mv, off);
      int   ol = __shfl_xor(ml, off);
      if (ov < mv || (ov == mv && ol < ml)) { mv = ov; ml = ol; }
    }
    t = mv;
    if (ml == lane) h++;
  }

  // rescan: accumulate strictly d < t; remember per-lane first d == t index
  float sx = 0.f, sy = 0.f, sz = 0.f, sr = 0.f;
  int cl = 0;
  int myNext = 0x7fffffff;
  for (int j = 0; j < CH; ++j) {
    int p = lane + 64 * j;
    float px, py, pz;
    if (S3) { px = P3[3*p]; py = P3[3*p+1]; pz = P3[3*p+2]; }
    else    { float4 f = P4[p]; px = f.x; py = f.y; pz = f.z; }
    float d = d2gram(px, py, pz, q.x, q.y, q.z, q2);
    if (d < t) { sx += px; sy += py; sz += pz; sr += sqrtf(fmaxf(d, 0.f)); cl++; }
    else if (d == t && myNext == 0x7fffffff) myNext = p;  // scan order => smallest p
  }
  int ctot = cl;
#pragma unroll
  for (int off = 32; off > 0; off >>= 1) ctot += __shfl_xor(ctot, off);
  int need = K - ctot;   // >= 1 (t itself), <= multiplicity of t
  float rt = sqrtf(fmaxf(t, 0.f));

  for (int e = 0; e < need; ++e) {
    int mn = myNext;
#pragma unroll
    for (int off = 32; off > 0; off >>= 1) mn = min(mn, __shfl_xor(mn, off));
    if (myNext == mn) {           // unique owner (index sets disjoint mod 64)
      float px, py, pz;
      if (S3) { px = P3[3*mn]; py = P3[3*mn+1]; pz = P3[3*mn+2]; }
      else    { float4 f = P4[mn]; px = f.x; py = f.y; pz = f.z; }
      sx += px; sy += py; sz += pz; sr += rt;
      int nx = 0x7fffffff;
      for (int j = (mn - lane) / 64 + 1; j < CH; ++j) {
        int p = lane + 64 * j;
        float ux, uy, uz;
        if (S3) { ux = P3[3*p]; uy = P3[3*p+1]; uz = P3[3*p+2]; }
        else    { float4 f = P4[p]; ux = f.x; uy = f.y; uz = f.z; }
        float d = d2gram(ux, uy, uz, q.x, q.y, q.z, q2);
        if (d == t) { nx = p; break; }
      }
      myNext = nx;
    }
  }

#pragma unroll
  for (int off = 32; off > 0; off >>= 1) {
    sx += __shfl_xor(sx, off);
    sy += __shfl_xor(sy, off);
    sz += __shfl_xor(sz, off);
    sr += __shfl_xor(sr, off);
  }
  if (lane == 0) {
    const float inv = 1.0f / (float)K;
    outc[qid] = make_float4(sx * inv, sy * inv, sz * inv, 0.f);
    outr[qid] = sr * inv;
  }
}

// ---------------------------------------------------------------------------
__global__ void gather1_kernel(const float* __restrict__ xyz,
                               const int* __restrict__ ids,
                               float4* __restrict__ cen)
{
  int g = blockIdx.x * 256 + threadIdx.x;
  if (g >= BATCH * M1) return;
  int b = g / M1;
  size_t base = ((size_t)b * NPTS + ids[g]) * 3;
  cen[g] = make_float4(xyz[base], xyz[base+1], xyz[base+2], 0.f);
}

__global__ void gather2_kernel(const float4* __restrict__ cen4,
                               const float* __restrict__ rad1,
                               const int* __restrict__ ids2,
                               float4* __restrict__ cen2,
                               float* __restrict__ radg)
{
  int g = blockIdx.x * 256 + threadIdx.x;
  if (g >= BATCH * SKP) return;
  int b = g / SKP;
  int p = ids2[g];
  cen2[g] = cen4[(size_t)b * M1 + p];
  radg[g] = rad1[(size_t)b * M1 + p];
}

__global__ void finalize_kernel(const float4* __restrict__ cen,
                                const float* __restrict__ radg,
                                const float* __restrict__ rad2,
                                const float* __restrict__ tmpl,
                                float* __restrict__ out)
{
  int g = blockIdx.x * 256 + threadIdx.x;   // one thread per sphere point
  int s = g >> 7;                            // sphere id 0..BATCH*SKP-1
  int j = g & 127;                           // template point id
  float4 c = cen[s];
  float r = __fmul_rn(__fadd_rn(radg[s], rad2[s]), 1.5f);
  float tx = tmpl[3*j], ty = tmpl[3*j+1], tz = tmpl[3*j+2];
  float* sp = out + BATCH * SKP * 3;
  sp[3*g]     = __fadd_rn(c.x, __fmul_rn(r, tx));
  sp[3*g + 1] = __fadd_rn(c.y, __fmul_rn(r, ty));
  sp[3*g + 2] = __fadd_rn(c.z, __fmul_rn(r, tz));
  if (j == 0) {
    out[3*s] = c.x; out[3*s+1] = c.y; out[3*s+2] = c.z;
    out[BATCH*SKP*3 + BATCH*SKP*SPHN*3 + s] = r;
  }
}

// ---------------------------------------------------------------------------
extern "C" void kernel_launch(void* const* d_in, const int* in_sizes, int n_in,
                              void* d_out, int out_size, void* d_ws, size_t ws_size,
                              hipStream_t stream)
{
  const float* xyz  = (const float*)d_in[0];   // f32 [B, N, 3]
  const float* tmpl = (const float*)d_in[1];   // f32 [128, 3]
  float* out = (float*)d_out;                  // f32 outputs
  char* ws = (char*)d_ws;

  // total ws footprint: 417,792 B
  int*    ids1  = (int*)   (ws + 0);        //  32768 B
  float4* cen4a = (float4*)(ws + 32768);    // 131072 B
  float4* cen4b = (float4*)(ws + 163840);   // 131072 B
  float*  rad1  = (float*) (ws + 294912);   //  32768 B
  int*    ids2  = (int*)   (ws + 327680);   //   8192 B
  float4* cen2a = (float4*)(ws + 335872);   //  32768 B
  float4* cen2b = (float4*)(ws + 368640);   //  32768 B
  float*  radg  = (float*) (ws + 401408);   //   8192 B
  float*  rad2  = (float*) (ws + 409600);   //   8192 B

  // Stage 1: FPS to 2048 seeds per batch
  fps1_kernel<<<BATCH, 1024, 0, stream>>>(xyz, ids1);
  gather1_kernel<<<(BATCH * M1 + 255) / 256, 256, 0, stream>>>(xyz, ids1, cen4a);
  // two skeletonization passes, k=32, against the full f32 cloud
  sklnz_kernel<KA, NPTS, true><<<BATCH * M1 / 4, 256, 0, stream>>>(cen4a, xyz, cen4b, rad1, M1);
  sklnz_kernel<KA, NPTS, true><<<BATCH * M1 / 4, 256, 0, stream>>>(cen4b, xyz, cen4a, rad1, M1);
  // Stage 2: FPS 2048 -> 512 on intermediate skeleton (cen4a)
  fps2_kernel<<<BATCH, 256, 0, stream>>>(cen4a, ids2);
  gather2_kernel<<<(BATCH * SKP + 255) / 256, 256, 0, stream>>>(cen4a, rad1, ids2, cen2a, radg);
  // two skeletonization passes, k=2, against the 2048-point skeleton
  sklnz_kernel<KB, M1, false><<<BATCH * SKP / 4, 256, 0, stream>>>(cen2a, cen4a, cen2b, rad2, SKP);
  sklnz_kernel<KB, M1, false><<<BATCH * SKP / 4, 256, 0, stream>>>(cen2b, cen4a, cen2a, rad2, SKP);
  // Outputs: centers, sphere points, radii (f32)
  finalize_kernel<<<BATCH * SKP * SPHN / 256, 256, 0, stream>>>(cen2a, radg, rad2, tmpl, out);
}

// Round 11
// 11070.557 us; speedup vs baseline: 2.0320x; 2.0320x over previous
//
#include <hip/hip_runtime.h>
#include <cstdint>

#define BATCH 4
#define NPTS  32768
#define HALFN 16384
#define SKP   512
#define M1    (SKP*4)   /* 2048 */
#define KA    32
#define KB    2
#define SPHN  128

// FPS distance: reference _fps uses sum((x-c)**2) = ((dx*dx+dy*dy)+dz*dz),
// pinned round-to-nearest, NO fma contraction (bitwise == numpy).
__device__ __forceinline__ float sqdist(float px, float py, float pz,
                                        float cx, float cy, float cz) {
  float dx = px - cx, dy = py - cy, dz = pz - cz;
  return __fadd_rn(__fadd_rn(__fmul_rn(dx, dx), __fmul_rn(dy, dy)),
                   __fmul_rn(dz, dz));
}
// sklnz distance: reference _pairwise_sqdist uses c2 + p2 - 2*cp (Gram form).
__device__ __forceinline__ float d2gram(float px, float py, float pz,
                                        float qx, float qy, float qz, float q2) {
  float p2 = __fadd_rn(__fadd_rn(__fmul_rn(px, px), __fmul_rn(py, py)),
                       __fmul_rn(pz, pz));
  float cp = __fadd_rn(__fadd_rn(__fmul_rn(qx, px), __fmul_rn(qy, py)),
                       __fmul_rn(qz, pz));
  return __fsub_rn(__fadd_rn(q2, p2), __fadd_rn(cp, cp));
}

// ---------------------------------------------------------------------------
// Stage-1 FPS, split across 2 blocks per batch (8 blocks total, 1 block/CU
// due to 128KB LDS -> all co-resident). Each block owns 16384 points:
// xy in LDS (float2, 128KB), z+dist in VGPRs (16+16 regs; total ~50 < the
// 64-VGPR cap the compiler pins for 1024-thread blocks -> no spill, R6-R10's
// 8.3us/iter scratch/stream latency wall removed).
// Cross-block handshake per iteration: 64-bit agent-scope atomic slot per
// (batch, parity, half): payload = valueBits<<32 | idx<<12 | it. Poison
// (0xAAA tag) never matches; cross-replay stale tags only match at equal it,
// where determinism makes stale payload == fresh payload (benign).
// Tie-break: strictly-greater wins, equal -> smaller global index.
// ---------------------------------------------------------------------------
__global__ __launch_bounds__(1024)
void fps1_kernel(const float* __restrict__ xyz, int* __restrict__ ids,
                 unsigned long long* __restrict__ sync)
{
  int blk = blockIdx.x;
  int b = blk >> 1, half = blk & 1;
  const float* X = xyz + (size_t)b * NPTS * 3;
  ids += (size_t)b * M1;
  int tid = threadIdx.x, lane = tid & 63, wave = tid >> 6;
  int base = half * HALFN;

  __shared__ float2 xysh[HALFN];       // 131072 B
  __shared__ float s_v[16];
  __shared__ int   s_i[16];
  __shared__ float s_piv[3];

  float zr[16], dist[16];
#pragma unroll
  for (int j = 0; j < 16; ++j) {
    int pl = tid + 1024 * j;
    int pg = base + pl;
    xysh[pl] = make_float2(X[3*pg], X[3*pg+1]);
    zr[j] = X[3*pg+2];
    dist[j] = 1e10f;
  }
  __syncthreads();

  if (half == 0 && tid == 0) ids[0] = 0;
  float cx = X[0], cy = X[1], cz = X[2];

  for (int it = 1; it < M1; ++it) {
    float best = -1.f; int besti = 0;
#pragma unroll
    for (int j = 0; j < 16; ++j) {
      int pl = tid + 1024 * j;
      float2 c2 = xysh[pl];
      float d = sqdist(c2.x, c2.y, zr[j], cx, cy, cz);
      d = fminf(dist[j], d);
      dist[j] = d;
      bool gt = d > best;
      best  = gt ? d : best;
      besti = gt ? (base + pl) : besti;
    }
    // wave argmax (tie -> smaller index)
#pragma unroll
    for (int off = 32; off > 0; off >>= 1) {
      float ov = __shfl_xor(best, off);
      int   oi = __shfl_xor(besti, off);
      if (ov > best || (ov == best && oi < besti)) { best = ov; besti = oi; }
    }
    if (lane == 0) { s_v[wave] = best; s_i[wave] = besti; }
    __syncthreads();                       // barrier 1
    if (tid == 0) {
      float v = s_v[0]; int i = s_i[0];
#pragma unroll
      for (int w = 1; w < 16; ++w) {
        float ov = s_v[w]; int oi = s_i[w];
        if (ov > v || (ov == v && oi < i)) { v = ov; i = oi; }
      }
      unsigned long long packed =
          ((unsigned long long)__float_as_uint(v) << 32) |
          ((unsigned)i << 12) | (unsigned)it;
      int si = b * 4 + (it & 1) * 2;
      __hip_atomic_store(&sync[si + half], packed,
                         __ATOMIC_RELEASE, __HIP_MEMORY_SCOPE_AGENT);
      unsigned long long rp;
      do {
        rp = __hip_atomic_load(&sync[si + (half ^ 1)],
                               __ATOMIC_ACQUIRE, __HIP_MEMORY_SCOPE_AGENT);
      } while ((unsigned)(rp & 0xFFFu) != (unsigned)it);
      float rv = __uint_as_float((unsigned)(rp >> 32));
      int   ri = (int)((rp >> 12) & 0x7FFFu);
      if (rv > v || (rv == v && ri < i)) { v = rv; i = ri; }
      if (half == 0) ids[it] = i;
      s_piv[0] = X[3*i]; s_piv[1] = X[3*i+1]; s_piv[2] = X[3*i+2];
    }
    __syncthreads();                       // barrier 2
    cx = s_piv[0]; cy = s_piv[1]; cz = s_piv[2];
  }
}

// ---------------------------------------------------------------------------
// Stage-2 FPS on the 2048-pt intermediate skeleton, LDS-staged (32KB).
// ---------------------------------------------------------------------------
__global__ __launch_bounds__(256)
void fps2_kernel(const float4* __restrict__ pts, int* __restrict__ ids)
{
  const int PTS = 8, BLOCK = 256, NW = 4;
  int b = blockIdx.x;
  pts += (size_t)b * M1;
  ids += (size_t)b * SKP;
  int tid = threadIdx.x, lane = tid & 63, wave = tid >> 6;

  __shared__ float4 pl[M1];            // 32768 B
  __shared__ float s_v[2][NW];
  __shared__ int   s_i[2][NW];

  float dist[PTS];
#pragma unroll
  for (int j = 0; j < PTS; ++j) {
    int p = tid + BLOCK * j;
    pl[p] = pts[p];
    dist[j] = 1e10f;
  }
  __syncthreads();

  if (tid == 0) ids[0] = 0;
  float4 piv = pl[0];
  float cx = piv.x, cy = piv.y, cz = piv.z;

  for (int it = 1; it < SKP; ++it) {
    float best = -1.f; int besti = 0;
#pragma unroll
    for (int j = 0; j < PTS; ++j) {
      int p = tid + BLOCK * j;
      float4 f = pl[p];
      float d = sqdist(f.x, f.y, f.z, cx, cy, cz);
      d = fminf(dist[j], d);
      dist[j] = d;
      bool gt = d > best;
      best  = gt ? d : best;
      besti = gt ? p : besti;
    }
#pragma unroll
    for (int off = 32; off > 0; off >>= 1) {
      float ov = __shfl_xor(best, off);
      int   oi = __shfl_xor(besti, off);
      if (ov > best || (ov == best && oi < besti)) { best = ov; besti = oi; }
    }
    int par = it & 1;
    if (lane == 0) { s_v[par][wave] = best; s_i[par][wave] = besti; }
    __syncthreads();
    float v = -1.f; int i = 0x7fffffff;
    if (lane < NW) { v = s_v[par][lane]; i = s_i[par][lane]; }
#pragma unroll
    for (int off = NW >> 1; off > 0; off >>= 1) {
      float ov = __shfl_xor(v, off);
      int   oi = __shfl_xor(i, off);
      if (ov > v || (ov == v && oi < i)) { v = ov; i = oi; }
    }
    i = __shfl(i, 0);
    if (tid == 0) ids[it] = i;
    float4 pv = pl[i];
    cx = pv.x; cy = pv.y; cz = pv.z;
  }
}

// ---------------------------------------------------------------------------
// Skeletonization: wave per query, GRAM-form distances, branch-free sorted
// top-K per lane, heads-merge -> exact K-th smallest t, exact-K tie fill.
// ---------------------------------------------------------------------------
template<int K, int N, bool S3>
__global__ __launch_bounds__(256)
void sklnz_kernel(const float4* __restrict__ queries,
                  const void*   __restrict__ ptsv,
                  float4* __restrict__ outc,
                  float*  __restrict__ outr,
                  int M)
{
  const int CH = N / 64;
  int wave = threadIdx.x >> 6, lane = threadIdx.x & 63;
  int qid = blockIdx.x * 4 + wave;
  int b = qid / M;
  const float*  P3 = (const float*)ptsv + (size_t)b * N * 3;
  const float4* P4 = (const float4*)ptsv + (size_t)b * N;
  float4 q = queries[qid];
  float q2 = __fadd_rn(__fadd_rn(__fmul_rn(q.x, q.x), __fmul_rn(q.y, q.y)),
                       __fmul_rn(q.z, q.z));

  float a[K];
#pragma unroll
  for (int s = 0; s < K; ++s) a[s] = 3.0e38f;

  for (int j = 0; j < CH; ++j) {
    int p = lane + 64 * j;
    float px, py, pz;
    if (S3) { px = P3[3*p]; py = P3[3*p+1]; pz = P3[3*p+2]; }
    else    { float4 f = P4[p]; px = f.x; py = f.y; pz = f.z; }
    float d = d2gram(px, py, pz, q.x, q.y, q.z, q2);
#pragma unroll
    for (int s = K - 1; s > 0; --s) a[s] = fminf(a[s], fmaxf(a[s-1], d));
    a[0] = fminf(a[0], d);
  }

  __shared__ float heads[4][64][K + 1];
#pragma unroll
  for (int s = 0; s < K; ++s) heads[wave][lane][s] = a[s];
  heads[wave][lane][K] = 3.1e38f;
  int h = 0; float t = 0.f;
  for (int r = 0; r < K; ++r) {
    float mv = heads[wave][lane][h];
    int   ml = lane;
#pragma unroll
    for (int off = 32; off > 0; off >>= 1) {
      float ov = __shfl_xor(mv, off);
      int   ol = __shfl_xor(ml, off);
      if (ov < mv || (ov == mv && ol < ml)) { mv = ov; ml = ol; }
    }
    t = mv;
    if (ml == lane) h++;
  }

  float sx = 0.f, sy = 0.f, sz = 0.f, sr = 0.f;
  int cl = 0;
  int myNext = 0x7fffffff;
  for (int j = 0; j < CH; ++j) {
    int p = lane + 64 * j;
    float px, py, pz;
    if (S3) { px = P3[3*p]; py = P3[3*p+1]; pz = P3[3*p+2]; }
    else    { float4 f = P4[p]; px = f.x; py = f.y; pz = f.z; }
    float d = d2gram(px, py, pz, q.x, q.y, q.z, q2);
    if (d < t) { sx += px; sy += py; sz += pz; sr += sqrtf(fmaxf(d, 0.f)); cl++; }
    else if (d == t && myNext == 0x7fffffff) myNext = p;
  }
  int ctot = cl;
#pragma unroll
  for (int off = 32; off > 0; off >>= 1) ctot += __shfl_xor(ctot, off);
  int need = K - ctot;
  float rt = sqrtf(fmaxf(t, 0.f));

  for (int e = 0; e < need; ++e) {
    int mn = myNext;
#pragma unroll
    for (int off = 32; off > 0; off >>= 1) mn = min(mn, __shfl_xor(mn, off));
    if (myNext == mn) {
      float px, py, pz;
      if (S3) { px = P3[3*mn]; py = P3[3*mn+1]; pz = P3[3*mn+2]; }
      else    { float4 f = P4[mn]; px = f.x; py = f.y; pz = f.z; }
      sx += px; sy += py; sz += pz; sr += rt;
      int nx = 0x7fffffff;
      for (int j = (mn - lane) / 64 + 1; j < CH; ++j) {
        int p = lane + 64 * j;
        float ux, uy, uz;
        if (S3) { ux = P3[3*p]; uy = P3[3*p+1]; uz = P3[3*p+2]; }
        else    { float4 f = P4[p]; ux = f.x; uy = f.y; uz = f.z; }
        float d = d2gram(ux, uy, uz, q.x, q.y, q.z, q2);
        if (d == t) { nx = p; break; }
      }
      myNext = nx;
    }
  }

#pragma unroll
  for (int off = 32; off > 0; off >>= 1) {
    sx += __shfl_xor(sx, off);
    sy += __shfl_xor(sy, off);
    sz += __shfl_xor(sz, off);
    sr += __shfl_xor(sr, off);
  }
  if (lane == 0) {
    const float inv = 1.0f / (float)K;
    outc[qid] = make_float4(sx * inv, sy * inv, sz * inv, 0.f);
    outr[qid] = sr * inv;
  }
}

// ---------------------------------------------------------------------------
__global__ void gather1_kernel(const float* __restrict__ xyz,
                               const int* __restrict__ ids,
                               float4* __restrict__ cen)
{
  int g = blockIdx.x * 256 + threadIdx.x;
  if (g >= BATCH * M1) return;
  int b = g / M1;
  size_t base = ((size_t)b * NPTS + ids[g]) * 3;
  cen[g] = make_float4(xyz[base], xyz[base+1], xyz[base+2], 0.f);
}

__global__ void gather2_kernel(const float4* __restrict__ cen4,
                               const float* __restrict__ rad1,
                               const int* __restrict__ ids2,
                               float4* __restrict__ cen2,
                               float* __restrict__ radg)
{
  int g = blockIdx.x * 256 + threadIdx.x;
  if (g >= BATCH * SKP) return;
  int b = g / SKP;
  int p = ids2[g];
  cen2[g] = cen4[(size_t)b * M1 + p];
  radg[g] = rad1[(size_t)b * M1 + p];
}

__global__ void finalize_kernel(const float4* __restrict__ cen,
                                const float* __restrict__ radg,
                                const float* __restrict__ rad2,
                                const float* __restrict__ tmpl,
                                float* __restrict__ out)
{
  int g = blockIdx.x * 256 + threadIdx.x;
  int s = g >> 7;
  int j = g & 127;
  float4 c = cen[s];
  float r = __fmul_rn(__fadd_rn(radg[s], rad2[s]), 1.5f);
  float tx = tmpl[3*j], ty = tmpl[3*j+1], tz = tmpl[3*j+2];
  float* sp = out + BATCH * SKP * 3;
  sp[3*g]     = __fadd_rn(c.x, __fmul_rn(r, tx));
  sp[3*g + 1] = __fadd_rn(c.y, __fmul_rn(r, ty));
  sp[3*g + 2] = __fadd_rn(c.z, __fmul_rn(r, tz));
  if (j == 0) {
    out[3*s] = c.x; out[3*s+1] = c.y; out[3*s+2] = c.z;
    out[BATCH*SKP*3 + BATCH*SKP*SPHN*3 + s] = r;
  }
}

// ---------------------------------------------------------------------------
extern "C" void kernel_launch(void* const* d_in, const int* in_sizes, int n_in,
                              void* d_out, int out_size, void* d_ws, size_t ws_size,
                              hipStream_t stream)
{
  const float* xyz  = (const float*)d_in[0];   // f32 [B, N, 3]
  const float* tmpl = (const float*)d_in[1];   // f32 [128, 3]
  float* out = (float*)d_out;                  // f32 outputs
  char* ws = (char*)d_ws;

  // total ws footprint: 417,920 B
  int*    ids1  = (int*)   (ws + 0);        //  32768 B
  float4* cen4a = (float4*)(ws + 32768);    // 131072 B
  float4* cen4b = (float4*)(ws + 163840);   // 131072 B
  float*  rad1  = (float*) (ws + 294912);   //  32768 B
  int*    ids2  = (int*)   (ws + 327680);   //   8192 B
  float4* cen2a = (float4*)(ws + 335872);   //  32768 B
  float4* cen2b = (float4*)(ws + 368640);   //  32768 B
  float*  radg  = (float*) (ws + 401408);   //   8192 B
  float*  rad2  = (float*) (ws + 409600);   //   8192 B
  unsigned long long* sync = (unsigned long long*)(ws + 417792); // 128 B

  // Stage 1: FPS to 2048 seeds per batch (2 blocks per batch, atomic handshake)
  fps1_kernel<<<BATCH * 2, 1024, 0, stream>>>(xyz, ids1, sync);
  gather1_kernel<<<(BATCH * M1 + 255) / 256, 256, 0, stream>>>(xyz, ids1, cen4a);
  // two skeletonization passes, k=32, against the full f32 cloud
  sklnz_kernel<KA, NPTS, true><<<BATCH * M1 / 4, 256, 0, stream>>>(cen4a, xyz, cen4b, rad1, M1);
  sklnz_kernel<KA, NPTS, true><<<BATCH * M1 / 4, 256, 0, stream>>>(cen4b, xyz, cen4a, rad1, M1);
  // Stage 2: FPS 2048 -> 512 on intermediate skeleton (cen4a)
  fps2_kernel<<<BATCH, 256, 0, stream>>>(cen4a, ids2);
  gather2_kernel<<<(BATCH * SKP + 255) / 256, 256, 0, stream>>>(cen4a, rad1, ids2, cen2a, radg);
  // two skeletonization passes, k=2, against the 2048-point skeleton
  sklnz_kernel<KB, M1, false><<<BATCH * SKP / 4, 256, 0, stream>>>(cen2a, cen4a, cen2b, rad2, SKP);
  sklnz_kernel<KB, M1, false><<<BATCH * SKP / 4, 256, 0, stream>>>(cen2b, cen4a, cen2a, rad2, SKP);
  // Outputs: centers, sphere points, radii (f32)
  finalize_kernel<<<BATCH * SKP * SPHN / 256, 256, 0, stream>>>(cen2a, radg, rad2, tmpl, out);
}

// Round 12
// 10643.723 us; speedup vs baseline: 2.1135x; 1.0401x over previous
//
#include <hip/hip_runtime.h>
#include <cstdint>

#define BATCH 4
#define NPTS  32768
#define QN    8192            /* points per fps1 block (4 blocks per batch) */
#define SKP   512
#define M1    (SKP*4)   /* 2048 */
#define KA    32
#define KB    2
#define SPHN  128

// FPS distance: reference _fps uses sum((x-c)**2) = ((dx*dx+dy*dy)+dz*dz),
// pinned round-to-nearest, NO fma contraction (bitwise == numpy).
__device__ __forceinline__ float sqdist(float px, float py, float pz,
                                        float cx, float cy, float cz) {
  float dx = px - cx, dy = py - cy, dz = pz - cz;
  return __fadd_rn(__fadd_rn(__fmul_rn(dx, dx), __fmul_rn(dy, dy)),
                   __fmul_rn(dz, dz));
}
// sklnz distance: reference _pairwise_sqdist uses c2 + p2 - 2*cp (Gram form).
__device__ __forceinline__ float d2gram(float px, float py, float pz,
                                        float qx, float qy, float qz, float q2) {
  float p2 = __fadd_rn(__fadd_rn(__fmul_rn(px, px), __fmul_rn(py, py)),
                       __fmul_rn(pz, pz));
  float cp = __fadd_rn(__fadd_rn(__fmul_rn(qx, px), __fmul_rn(qy, py)),
                       __fmul_rn(qz, pz));
  return __fsub_rn(__fadd_rn(q2, p2), __fadd_rn(cp, cp));
}

// ---------------------------------------------------------------------------
// Stage-1 FPS, split across 4 blocks per batch (16 blocks total, trivially
// co-resident). Each block owns 8192 points: xy in LDS (float2, 64KB),
// z[8]+dist[8] in VGPRs (~40 regs < the 64-VGPR cap -> no spill).
// Per-iteration 4-way handshake via agent-scope 64-bit atomics:
// payload = valueBits<<32 | idx<<12 | it; parity-indexed slot pairs.
// Poison tag 0xAAA (2730) > max it (2047) never matches; cross-replay stale
// tags only match at equal it where determinism makes the stale payload
// bit-identical (benign). Tie-break: greater value wins, equal -> smaller
// global index (jnp.argmax first-occurrence).
// R11 measured: compute ~1.4us/iter (2-way, 16pts) + ~2.6us handshake;
// 4-way halves compute and skew.
// ---------------------------------------------------------------------------
__global__ __launch_bounds__(1024)
void fps1_kernel(const float* __restrict__ xyz, int* __restrict__ ids,
                 unsigned long long* __restrict__ sync)
{
  int blk = blockIdx.x;
  int b = blk >> 2, sub = blk & 3;
  const float* X = xyz + (size_t)b * NPTS * 3;
  ids += (size_t)b * M1;
  int tid = threadIdx.x, lane = tid & 63, wave = tid >> 6;
  int base = sub * QN;

  __shared__ float2 xysh[QN];          // 65536 B
  __shared__ float s_v[16];
  __shared__ int   s_i[16];
  __shared__ float s_piv[3];

  float zr[8], dist[8];
#pragma unroll
  for (int j = 0; j < 8; ++j) {
    int pl = tid + 1024 * j;
    int pg = base + pl;
    xysh[pl] = make_float2(X[3*pg], X[3*pg+1]);
    zr[j] = X[3*pg+2];
    dist[j] = 1e10f;
  }
  __syncthreads();

  if (sub == 0 && tid == 0) ids[0] = 0;
  float cx = X[0], cy = X[1], cz = X[2];

  for (int it = 1; it < M1; ++it) {
    float best = -1.f; int besti = 0;
#pragma unroll
    for (int j = 0; j < 8; ++j) {
      int pl = tid + 1024 * j;
      float2 c2 = xysh[pl];
      float d = sqdist(c2.x, c2.y, zr[j], cx, cy, cz);
      d = fminf(dist[j], d);
      dist[j] = d;
      bool gt = d > best;
      best  = gt ? d : best;
      besti = gt ? (base + pl) : besti;
    }
    // wave argmax (tie -> smaller index)
#pragma unroll
    for (int off = 32; off > 0; off >>= 1) {
      float ov = __shfl_xor(best, off);
      int   oi = __shfl_xor(besti, off);
      if (ov > best || (ov == best && oi < besti)) { best = ov; besti = oi; }
    }
    if (lane == 0) { s_v[wave] = best; s_i[wave] = besti; }
    __syncthreads();                       // barrier 1
    if (tid == 0) {
      float v = s_v[0]; int i = s_i[0];
#pragma unroll
      for (int w = 1; w < 16; ++w) {
        float ov = s_v[w]; int oi = s_i[w];
        if (ov > v || (ov == v && oi < i)) { v = ov; i = oi; }
      }
      unsigned long long packed =
          ((unsigned long long)__float_as_uint(v) << 32) |
          ((unsigned)i << 12) | (unsigned)it;
      int si = b * 8 + (it & 1) * 4;
      __hip_atomic_store(&sync[si + sub], packed,
                         __ATOMIC_RELEASE, __HIP_MEMORY_SCOPE_AGENT);
      int s0 = si + ((sub + 1) & 3);
      int s1 = si + ((sub + 2) & 3);
      int s2 = si + ((sub + 3) & 3);
      unsigned long long o0, o1, o2;
      for (;;) {
        o0 = __hip_atomic_load(&sync[s0], __ATOMIC_ACQUIRE, __HIP_MEMORY_SCOPE_AGENT);
        o1 = __hip_atomic_load(&sync[s1], __ATOMIC_ACQUIRE, __HIP_MEMORY_SCOPE_AGENT);
        o2 = __hip_atomic_load(&sync[s2], __ATOMIC_ACQUIRE, __HIP_MEMORY_SCOPE_AGENT);
        if ((unsigned)(o0 & 0xFFFu) == (unsigned)it &&
            (unsigned)(o1 & 0xFFFu) == (unsigned)it &&
            (unsigned)(o2 & 0xFFFu) == (unsigned)it) break;
      }
#pragma unroll
      for (int r = 0; r < 3; ++r) {
        unsigned long long rp = (r == 0) ? o0 : (r == 1) ? o1 : o2;
        float rv = __uint_as_float((unsigned)(rp >> 32));
        int   ri = (int)((rp >> 12) & 0x7FFFu);
        if (rv > v || (rv == v && ri < i)) { v = rv; i = ri; }
      }
      if (sub == 0) ids[it] = i;
      s_piv[0] = X[3*i]; s_piv[1] = X[3*i+1]; s_piv[2] = X[3*i+2];
    }
    __syncthreads();                       // barrier 2
    cx = s_piv[0]; cy = s_piv[1]; cz = s_piv[2];
  }
}

// ---------------------------------------------------------------------------
// Stage-2 FPS on the 2048-pt intermediate skeleton, LDS-staged (32KB).
// ---------------------------------------------------------------------------
__global__ __launch_bounds__(256)
void fps2_kernel(const float4* __restrict__ pts, int* __restrict__ ids)
{
  const int PTS = 8, BLOCK = 256, NW = 4;
  int b = blockIdx.x;
  pts += (size_t)b * M1;
  ids += (size_t)b * SKP;
  int tid = threadIdx.x, lane = tid & 63, wave = tid >> 6;

  __shared__ float4 pl[M1];            // 32768 B
  __shared__ float s_v[2][NW];
  __shared__ int   s_i[2][NW];

  float dist[PTS];
#pragma unroll
  for (int j = 0; j < PTS; ++j) {
    int p = tid + BLOCK * j;
    pl[p] = pts[p];
    dist[j] = 1e10f;
  }
  __syncthreads();

  if (tid == 0) ids[0] = 0;
  float4 piv = pl[0];
  float cx = piv.x, cy = piv.y, cz = piv.z;

  for (int it = 1; it < SKP; ++it) {
    float best = -1.f; int besti = 0;
#pragma unroll
    for (int j = 0; j < PTS; ++j) {
      int p = tid + BLOCK * j;
      float4 f = pl[p];
      float d = sqdist(f.x, f.y, f.z, cx, cy, cz);
      d = fminf(dist[j], d);
      dist[j] = d;
      bool gt = d > best;
      best  = gt ? d : best;
      besti = gt ? p : besti;
    }
#pragma unroll
    for (int off = 32; off > 0; off >>= 1) {
      float ov = __shfl_xor(best, off);
      int   oi = __shfl_xor(besti, off);
      if (ov > best || (ov == best && oi < besti)) { best = ov; besti = oi; }
    }
    int par = it & 1;
    if (lane == 0) { s_v[par][wave] = best; s_i[par][wave] = besti; }
    __syncthreads();
    float v = -1.f; int i = 0x7fffffff;
    if (lane < NW) { v = s_v[par][lane]; i = s_i[par][lane]; }
#pragma unroll
    for (int off = NW >> 1; off > 0; off >>= 1) {
      float ov = __shfl_xor(v, off);
      int   oi = __shfl_xor(i, off);
      if (ov > v || (ov == v && oi < i)) { v = ov; i = oi; }
    }
    i = __shfl(i, 0);
    if (tid == 0) ids[it] = i;
    float4 pv = pl[i];
    cx = pv.x; cy = pv.y; cz = pv.z;
  }
}

// ---------------------------------------------------------------------------
// Skeletonization: wave per query, GRAM-form distances, branch-free sorted
// top-K per lane, heads-merge -> exact K-th smallest t, exact-K tie fill.
// ---------------------------------------------------------------------------
template<int K, int N, bool S3>
__global__ __launch_bounds__(256)
void sklnz_kernel(const float4* __restrict__ queries,
                  const void*   __restrict__ ptsv,
                  float4* __restrict__ outc,
                  float*  __restrict__ outr,
                  int M)
{
  const int CH = N / 64;
  int wave = threadIdx.x >> 6, lane = threadIdx.x & 63;
  int qid = blockIdx.x * 4 + wave;
  int b = qid / M;
  const float*  P3 = (const float*)ptsv + (size_t)b * N * 3;
  const float4* P4 = (const float4*)ptsv + (size_t)b * N;
  float4 q = queries[qid];
  float q2 = __fadd_rn(__fadd_rn(__fmul_rn(q.x, q.x), __fmul_rn(q.y, q.y)),
                       __fmul_rn(q.z, q.z));

  float a[K];
#pragma unroll
  for (int s = 0; s < K; ++s) a[s] = 3.0e38f;

  for (int j = 0; j < CH; ++j) {
    int p = lane + 64 * j;
    float px, py, pz;
    if (S3) { px = P3[3*p]; py = P3[3*p+1]; pz = P3[3*p+2]; }
    else    { float4 f = P4[p]; px = f.x; py = f.y; pz = f.z; }
    float d = d2gram(px, py, pz, q.x, q.y, q.z, q2);
#pragma unroll
    for (int s = K - 1; s > 0; --s) a[s] = fminf(a[s], fmaxf(a[s-1], d));
    a[0] = fminf(a[0], d);
  }

  __shared__ float heads[4][64][K + 1];
#pragma unroll
  for (int s = 0; s < K; ++s) heads[wave][lane][s] = a[s];
  heads[wave][lane][K] = 3.1e38f;
  int h = 0; float t = 0.f;
  for (int r = 0; r < K; ++r) {
    float mv = heads[wave][lane][h];
    int   ml = lane;
#pragma unroll
    for (int off = 32; off > 0; off >>= 1) {
      float ov = __shfl_xor(mv, off);
      int   ol = __shfl_xor(ml, off);
      if (ov < mv || (ov == mv && ol < ml)) { mv = ov; ml = ol; }
    }
    t = mv;
    if (ml == lane) h++;
  }

  float sx = 0.f, sy = 0.f, sz = 0.f, sr = 0.f;
  int cl = 0;
  int myNext = 0x7fffffff;
  for (int j = 0; j < CH; ++j) {
    int p = lane + 64 * j;
    float px, py, pz;
    if (S3) { px = P3[3*p]; py = P3[3*p+1]; pz = P3[3*p+2]; }
    else    { float4 f = P4[p]; px = f.x; py = f.y; pz = f.z; }
    float d = d2gram(px, py, pz, q.x, q.y, q.z, q2);
    if (d < t) { sx += px; sy += py; sz += pz; sr += sqrtf(fmaxf(d, 0.f)); cl++; }
    else if (d == t && myNext == 0x7fffffff) myNext = p;
  }
  int ctot = cl;
#pragma unroll
  for (int off = 32; off > 0; off >>= 1) ctot += __shfl_xor(ctot, off);
  int need = K - ctot;
  float rt = sqrtf(fmaxf(t, 0.f));

  for (int e = 0; e < need; ++e) {
    int mn = myNext;
#pragma unroll
    for (int off = 32; off > 0; off >>= 1) mn = min(mn, __shfl_xor(mn, off));
    if (myNext == mn) {
      float px, py, pz;
      if (S3) { px = P3[3*mn]; py = P3[3*mn+1]; pz = P3[3*mn+2]; }
      else    { float4 f = P4[mn]; px = f.x; py = f.y; pz = f.z; }
      sx += px; sy += py; sz += pz; sr += rt;
      int nx = 0x7fffffff;
      for (int j = (mn - lane) / 64 + 1; j < CH; ++j) {
        int p = lane + 64 * j;
        float ux, uy, uz;
        if (S3) { ux = P3[3*p]; uy = P3[3*p+1]; uz = P3[3*p+2]; }
        else    { float4 f = P4[p]; ux = f.x; uy = f.y; uz = f.z; }
        float d = d2gram(ux, uy, uz, q.x, q.y, q.z, q2);
        if (d == t) { nx = p; break; }
      }
      myNext = nx;
    }
  }

#pragma unroll
  for (int off = 32; off > 0; off >>= 1) {
    sx += __shfl_xor(sx, off);
    sy += __shfl_xor(sy, off);
    sz += __shfl_xor(sz, off);
    sr += __shfl_xor(sr, off);
  }
  if (lane == 0) {
    const float inv = 1.0f / (float)K;
    outc[qid] = make_float4(sx * inv, sy * inv, sz * inv, 0.f);
    outr[qid] = sr * inv;
  }
}

// ---------------------------------------------------------------------------
__global__ void gather1_kernel(const float* __restrict__ xyz,
                               const int* __restrict__ ids,
                               float4* __restrict__ cen)
{
  int g = blockIdx.x * 256 + threadIdx.x;
  if (g >= BATCH * M1) return;
  int b = g / M1;
  size_t base = ((size_t)b * NPTS + ids[g]) * 3;
  cen[g] = make_float4(xyz[base], xyz[base+1], xyz[base+2], 0.f);
}

__global__ void gather2_kernel(const float4* __restrict__ cen4,
                               const float* __restrict__ rad1,
                               const int* __restrict__ ids2,
                               float4* __restrict__ cen2,
                               float* __restrict__ radg)
{
  int g = blockIdx.x * 256 + threadIdx.x;
  if (g >= BATCH * SKP) return;
  int b = g / SKP;
  int p = ids2[g];
  cen2[g] = cen4[(size_t)b * M1 + p];
  radg[g] = rad1[(size_t)b * M1 + p];
}

__global__ void finalize_kernel(const float4* __restrict__ cen,
                                const float* __restrict__ radg,
                                const float* __restrict__ rad2,
                                const float* __restrict__ tmpl,
                                float* __restrict__ out)
{
  int g = blockIdx.x * 256 + threadIdx.x;
  int s = g >> 7;
  int j = g & 127;
  float4 c = cen[s];
  float r = __fmul_rn(__fadd_rn(radg[s], rad2[s]), 1.5f);
  float tx = tmpl[3*j], ty = tmpl[3*j+1], tz = tmpl[3*j+2];
  float* sp = out + BATCH * SKP * 3;
  sp[3*g]     = __fadd_rn(c.x, __fmul_rn(r, tx));
  sp[3*g + 1] = __fadd_rn(c.y, __fmul_rn(r, ty));
  sp[3*g + 2] = __fadd_rn(c.z, __fmul_rn(r, tz));
  if (j == 0) {
    out[3*s] = c.x; out[3*s+1] = c.y; out[3*s+2] = c.z;
    out[BATCH*SKP*3 + BATCH*SKP*SPHN*3 + s] = r;
  }
}

// ---------------------------------------------------------------------------
extern "C" void kernel_launch(void* const* d_in, const int* in_sizes, int n_in,
                              void* d_out, int out_size, void* d_ws, size_t ws_size,
                              hipStream_t stream)
{
  const float* xyz  = (const float*)d_in[0];   // f32 [B, N, 3]
  const float* tmpl = (const float*)d_in[1];   // f32 [128, 3]
  float* out = (float*)d_out;                  // f32 outputs
  char* ws = (char*)d_ws;

  // total ws footprint: 418,048 B
  int*    ids1  = (int*)   (ws + 0);        //  32768 B
  float4* cen4a = (float4*)(ws + 32768);    // 131072 B
  float4* cen4b = (float4*)(ws + 163840);   // 131072 B
  float*  rad1  = (float*) (ws + 294912);   //  32768 B
  int*    ids2  = (int*)   (ws + 327680);   //   8192 B
  float4* cen2a = (float4*)(ws + 335872);   //  32768 B
  float4* cen2b = (float4*)(ws + 368640);   //  32768 B
  float*  radg  = (float*) (ws + 401408);   //   8192 B
  float*  rad2  = (float*) (ws + 409600);   //   8192 B
  unsigned long long* sync = (unsigned long long*)(ws + 417792); // 256 B

  // Stage 1: FPS to 2048 seeds per batch (4 blocks per batch, atomic handshake)
  fps1_kernel<<<BATCH * 4, 1024, 0, stream>>>(xyz, ids1, sync);
  gather1_kernel<<<(BATCH * M1 + 255) / 256, 256, 0, stream>>>(xyz, ids1, cen4a);
  // two skeletonization passes, k=32, against the full f32 cloud
  sklnz_kernel<KA, NPTS, true><<<BATCH * M1 / 4, 256, 0, stream>>>(cen4a, xyz, cen4b, rad1, M1);
  sklnz_kernel<KA, NPTS, true><<<BATCH * M1 / 4, 256, 0, stream>>>(cen4b, xyz, cen4a, rad1, M1);
  // Stage 2: FPS 2048 -> 512 on intermediate skeleton (cen4a)
  fps2_kernel<<<BATCH, 256, 0, stream>>>(cen4a, ids2);
  gather2_kernel<<<(BATCH * SKP + 255) / 256, 256, 0, stream>>>(cen4a, rad1, ids2, cen2a, radg);
  // two skeletonization passes, k=2, against the 2048-point skeleton
  sklnz_kernel<KB, M1, false><<<BATCH * SKP / 4, 256, 0, stream>>>(cen2a, cen4a, cen2b, rad2, SKP);
  sklnz_kernel<KB, M1, false><<<BATCH * SKP / 4, 256, 0, stream>>>(cen2b, cen4a, cen2a, rad2, SKP);
  // Outputs: centers, sphere points, radii (f32)
  finalize_kernel<<<BATCH * SKP * SPHN / 256, 256, 0, stream>>>(cen2a, radg, rad2, tmpl, out);
}

// Round 13
// 7542.612 us; speedup vs baseline: 2.9824x; 1.4111x over previous
//
#include <hip/hip_runtime.h>
#include <cstdint>

#define BATCH 4
#define NPTS  32768
#define QN    8192            /* points per fps1 block (4 blocks per batch) */
#define SKP   512
#define M1    (SKP*4)   /* 2048 */
#define KA    32
#define KB    2
#define SPHN  128

// FPS distance: reference _fps uses sum((x-c)**2) = ((dx*dx+dy*dy)+dz*dz),
// pinned round-to-nearest, NO fma contraction (bitwise == numpy).
__device__ __forceinline__ float sqdist(float px, float py, float pz,
                                        float cx, float cy, float cz) {
  float dx = px - cx, dy = py - cy, dz = pz - cz;
  return __fadd_rn(__fadd_rn(__fmul_rn(dx, dx), __fmul_rn(dy, dy)),
                   __fmul_rn(dz, dz));
}
// sklnz distance: reference _pairwise_sqdist uses c2 + p2 - 2*cp (Gram form).
__device__ __forceinline__ float d2gram(float px, float py, float pz,
                                        float qx, float qy, float qz, float q2) {
  float p2 = __fadd_rn(__fadd_rn(__fmul_rn(px, px), __fmul_rn(py, py)),
                       __fmul_rn(pz, pz));
  float cp = __fadd_rn(__fadd_rn(__fmul_rn(qx, px), __fmul_rn(qy, py)),
                       __fmul_rn(qz, pz));
  return __fsub_rn(__fadd_rn(q2, p2), __fadd_rn(cp, cp));
}

// ---------------------------------------------------------------------------
// Stage-1 FPS, 4 blocks per batch. xy in LDS (64KB), z[8]+dist[8] in VGPRs.
// R12 post-mortem: per-iter 3.9us of which ~3.5us was a tid0-serial tail
// (16 dependent LDS loads + serial 3-slot poll + serial pivot load). This
// round the whole tail runs parallel on wave 0: lane<16 shfl-reduce, lane 0
// publishes, lanes 1-3 poll remote slots concurrently, 2-shfl final reduce,
// lanes 0-2 load pivot coords in parallel.
// Handshake protocol (proven R11/R12): payload = valueBits<<32|idx<<12|it,
// parity-indexed slot pairs; poison tag 0xAAA>2047 never matches; stale
// cross-replay matches are bit-identical by determinism (benign).
// Tie-break: greater wins, equal -> smaller global index (jnp.argmax).
// ---------------------------------------------------------------------------
__global__ __launch_bounds__(1024)
void fps1_kernel(const float* __restrict__ xyz, int* __restrict__ ids,
                 unsigned long long* __restrict__ sync)
{
  int blk = blockIdx.x;
  int b = blk >> 2, sub = blk & 3;
  const float* X = xyz + (size_t)b * NPTS * 3;
  ids += (size_t)b * M1;
  int tid = threadIdx.x, lane = tid & 63, wave = tid >> 6;
  int base = sub * QN;

  __shared__ float2 xysh[QN];          // 65536 B
  __shared__ float s_v[16];
  __shared__ int   s_i[16];
  __shared__ float s_piv[3];

  float zr[8], dist[8];
#pragma unroll
  for (int j = 0; j < 8; ++j) {
    int pl = tid + 1024 * j;
    int pg = base + pl;
    xysh[pl] = make_float2(X[3*pg], X[3*pg+1]);
    zr[j] = X[3*pg+2];
    dist[j] = 1e10f;
  }
  __syncthreads();

  if (sub == 0 && tid == 0) ids[0] = 0;
  float cx = X[0], cy = X[1], cz = X[2];

  for (int it = 1; it < M1; ++it) {
    float best = -1.f; int besti = 0;
#pragma unroll
    for (int j = 0; j < 8; ++j) {
      int pl = tid + 1024 * j;
      float2 c2 = xysh[pl];
      float d = sqdist(c2.x, c2.y, zr[j], cx, cy, cz);
      d = fminf(dist[j], d);
      dist[j] = d;
      bool gt = d > best;
      best  = gt ? d : best;
      besti = gt ? (base + pl) : besti;
    }
    // wave argmax (tie -> smaller index)
#pragma unroll
    for (int off = 32; off > 0; off >>= 1) {
      float ov = __shfl_xor(best, off);
      int   oi = __shfl_xor(besti, off);
      if (ov > best || (ov == best && oi < besti)) { best = ov; besti = oi; }
    }
    if (lane == 0) { s_v[wave] = best; s_i[wave] = besti; }
    __syncthreads();                       // barrier 1
    if (wave == 0) {
      float v = -1.f; int i = 0x7fffffff;
      if (lane < 16) { v = s_v[lane]; i = s_i[lane]; }
#pragma unroll
      for (int off = 8; off > 0; off >>= 1) {
        float ov = __shfl_xor(v, off);
        int   oi = __shfl_xor(i, off);
        if (ov > v || (ov == v && oi < i)) { v = ov; i = oi; }
      }
      v = __shfl(v, 0); i = __shfl(i, 0);  // block winner -> all lanes
      unsigned long long packed =
          ((unsigned long long)__float_as_uint(v) << 32) |
          ((unsigned)i << 12) | (unsigned)it;
      int si = b * 8 + (it & 1) * 4;
      if (lane == 0)
        __hip_atomic_store(&sync[si + sub], packed,
                           __ATOMIC_RELEASE, __HIP_MEMORY_SCOPE_AGENT);
      unsigned long long rp = packed;      // lanes !=1..3 carry local candidate
      if (lane >= 1 && lane <= 3) {
        int rs = si + ((sub + lane) & 3);
        do {
          rp = __hip_atomic_load(&sync[rs],
                                 __ATOMIC_ACQUIRE, __HIP_MEMORY_SCOPE_AGENT);
        } while ((unsigned)(rp & 0xFFFu) != (unsigned)it);
      }
      float cv = __uint_as_float((unsigned)(rp >> 32));
      int   ci = (int)((rp >> 12) & 0x7FFFu);
      // reduce candidates over lanes 0..3 (higher lanes reduce duplicates)
#pragma unroll
      for (int off = 2; off > 0; off >>= 1) {
        float ov = __shfl_xor(cv, off);
        int   oi = __shfl_xor(ci, off);
        if (ov > cv || (ov == cv && oi < ci)) { cv = ov; ci = oi; }
      }
      ci = __shfl(ci, 0);
      if (lane == 0 && sub == 0) ids[it] = ci;
      if (lane < 3) s_piv[lane] = X[3 * ci + lane];
    }
    __syncthreads();                       // barrier 2
    cx = s_piv[0]; cy = s_piv[1]; cz = s_piv[2];
  }
}

// ---------------------------------------------------------------------------
// Stage-2 FPS on the 2048-pt intermediate skeleton, LDS-staged (32KB).
// ---------------------------------------------------------------------------
__global__ __launch_bounds__(256)
void fps2_kernel(const float4* __restrict__ pts, int* __restrict__ ids)
{
  const int PTS = 8, BLOCK = 256, NW = 4;
  int b = blockIdx.x;
  pts += (size_t)b * M1;
  ids += (size_t)b * SKP;
  int tid = threadIdx.x, lane = tid & 63, wave = tid >> 6;

  __shared__ float4 pl[M1];            // 32768 B
  __shared__ float s_v[2][NW];
  __shared__ int   s_i[2][NW];

  float dist[PTS];
#pragma unroll
  for (int j = 0; j < PTS; ++j) {
    int p = tid + BLOCK * j;
    pl[p] = pts[p];
    dist[j] = 1e10f;
  }
  __syncthreads();

  if (tid == 0) ids[0] = 0;
  float4 piv = pl[0];
  float cx = piv.x, cy = piv.y, cz = piv.z;

  for (int it = 1; it < SKP; ++it) {
    float best = -1.f; int besti = 0;
#pragma unroll
    for (int j = 0; j < PTS; ++j) {
      int p = tid + BLOCK * j;
      float4 f = pl[p];
      float d = sqdist(f.x, f.y, f.z, cx, cy, cz);
      d = fminf(dist[j], d);
      dist[j] = d;
      bool gt = d > best;
      best  = gt ? d : best;
      besti = gt ? p : besti;
    }
#pragma unroll
    for (int off = 32; off > 0; off >>= 1) {
      float ov = __shfl_xor(best, off);
      int   oi = __shfl_xor(besti, off);
      if (ov > best || (ov == best && oi < besti)) { best = ov; besti = oi; }
    }
    int par = it & 1;
    if (lane == 0) { s_v[par][wave] = best; s_i[par][wave] = besti; }
    __syncthreads();
    float v = -1.f; int i = 0x7fffffff;
    if (lane < NW) { v = s_v[par][lane]; i = s_i[par][lane]; }
#pragma unroll
    for (int off = NW >> 1; off > 0; off >>= 1) {
      float ov = __shfl_xor(v, off);
      int   oi = __shfl_xor(i, off);
      if (ov > v || (ov == v && oi < i)) { v = ov; i = oi; }
    }
    i = __shfl(i, 0);
    if (tid == 0) ids[it] = i;
    float4 pv = pl[i];
    cx = pv.x; cy = pv.y; cz = pv.z;
  }
}

// ---------------------------------------------------------------------------
// Skeletonization: wave per query, GRAM-form distances.
// Fast path: per-lane sorted top-KL (KL=8 for K=32), heads-merge K rounds
// -> t. Subset argument: t >= t_true always; rescan counts strict-less over
// ALL points, so ctot >= K detects t > t_true exactly -> rare (P~1e-7)
// fallback recomputes with full per-lane top-K. Tie-fill (exact lax.top_k
// semantics) runs on the verified t.
// ---------------------------------------------------------------------------
template<int K, int KL, int N, bool S3>
__global__ __launch_bounds__(256)
void sklnz_kernel(const float4* __restrict__ queries,
                  const void*   __restrict__ ptsv,
                  float4* __restrict__ outc,
                  float*  __restrict__ outr,
                  int M)
{
  const int CH = N / 64;
  int wave = threadIdx.x >> 6, lane = threadIdx.x & 63;
  int qid = blockIdx.x * 4 + wave;
  int b = qid / M;
  const float*  P3 = (const float*)ptsv + (size_t)b * N * 3;
  const float4* P4 = (const float4*)ptsv + (size_t)b * N;
  float4 q = queries[qid];
  float q2 = __fadd_rn(__fadd_rn(__fmul_rn(q.x, q.x), __fmul_rn(q.y, q.y)),
                       __fmul_rn(q.z, q.z));

  __shared__ float heads[4][64][K + 1];

  // ---- fast scan: per-lane sorted top-KL ----
  float a[KL];
#pragma unroll
  for (int s = 0; s < KL; ++s) a[s] = 3.0e38f;
  for (int j = 0; j < CH; ++j) {
    int p = lane + 64 * j;
    float px, py, pz;
    if (S3) { px = P3[3*p]; py = P3[3*p+1]; pz = P3[3*p+2]; }
    else    { float4 f = P4[p]; px = f.x; py = f.y; pz = f.z; }
    float d = d2gram(px, py, pz, q.x, q.y, q.z, q2);
#pragma unroll
    for (int s = KL - 1; s > 0; --s) a[s] = fminf(a[s], fmaxf(a[s-1], d));
    a[0] = fminf(a[0], d);
  }
  // ---- merge: K rounds over per-lane lists (sentinel-terminated) ----
#pragma unroll
  for (int s = 0; s < KL; ++s) heads[wave][lane][s] = a[s];
  heads[wave][lane][KL] = 3.1e38f;
  int h = 0; float t = 0.f;
  for (int r = 0; r < K; ++r) {
    float mv = heads[wave][lane][h];
    int   ml = lane;
#pragma unroll
    for (int off = 32; off > 0; off >>= 1) {
      float ov = __shfl_xor(mv, off);
      int   ol = __shfl_xor(ml, off);
      if (ov < mv || (ov == mv && ol < ml)) { mv = ov; ml = ol; }
    }
    t = mv;
    if (ml == lane) h++;
  }

  // ---- rescan: accumulate d < t, count, per-lane first d == t ----
  float sx = 0.f, sy = 0.f, sz = 0.f, sr = 0.f;
  int cl = 0;
  int myNext = 0x7fffffff;
  for (int j = 0; j < CH; ++j) {
    int p = lane + 64 * j;
    float px, py, pz;
    if (S3) { px = P3[3*p]; py = P3[3*p+1]; pz = P3[3*p+2]; }
    else    { float4 f = P4[p]; px = f.x; py = f.y; pz = f.z; }
    float d = d2gram(px, py, pz, q.x, q.y, q.z, q2);
    if (d < t) { sx += px; sy += py; sz += pz; sr += sqrtf(fmaxf(d, 0.f)); cl++; }
    else if (d == t && myNext == 0x7fffffff) myNext = p;
  }
  int ctot = cl;
#pragma unroll
  for (int off = 32; off > 0; off >>= 1) ctot += __shfl_xor(ctot, off);

  if constexpr (KL < K) {
    if (ctot >= K) {
      // ---- exact fallback: full per-lane top-K (probability ~1e-7) ----
      float a2[K];
#pragma unroll
      for (int s = 0; s < K; ++s) a2[s] = 3.0e38f;
      for (int j = 0; j < CH; ++j) {
        int p = lane + 64 * j;
        float px, py, pz;
        if (S3) { px = P3[3*p]; py = P3[3*p+1]; pz = P3[3*p+2]; }
        else    { float4 f = P4[p]; px = f.x; py = f.y; pz = f.z; }
        float d = d2gram(px, py, pz, q.x, q.y, q.z, q2);
#pragma unroll
        for (int s = K - 1; s > 0; --s) a2[s] = fminf(a2[s], fmaxf(a2[s-1], d));
        a2[0] = fminf(a2[0], d);
      }
#pragma unroll
      for (int s = 0; s < K; ++s) heads[wave][lane][s] = a2[s];
      heads[wave][lane][K] = 3.1e38f;
      h = 0;
      for (int r = 0; r < K; ++r) {
        float mv = heads[wave][lane][h];
        int   ml = lane;
#pragma unroll
        for (int off = 32; off > 0; off >>= 1) {
          float ov = __shfl_xor(mv, off);
          int   ol = __shfl_xor(ml, off);
          if (ov < mv || (ov == mv && ol < ml)) { mv = ov; ml = ol; }
        }
        t = mv;
        if (ml == lane) h++;
      }
      sx = sy = sz = sr = 0.f; cl = 0; myNext = 0x7fffffff;
      for (int j = 0; j < CH; ++j) {
        int p = lane + 64 * j;
        float px, py, pz;
        if (S3) { px = P3[3*p]; py = P3[3*p+1]; pz = P3[3*p+2]; }
        else    { float4 f = P4[p]; px = f.x; py = f.y; pz = f.z; }
        float d = d2gram(px, py, pz, q.x, q.y, q.z, q2);
        if (d < t) { sx += px; sy += py; sz += pz; sr += sqrtf(fmaxf(d, 0.f)); cl++; }
        else if (d == t && myNext == 0x7fffffff) myNext = p;
      }
      ctot = cl;
#pragma unroll
      for (int off = 32; off > 0; off >>= 1) ctot += __shfl_xor(ctot, off);
    }
  }

  int need = K - ctot;               // >= 1, <= multiplicity of t
  float rt = sqrtf(fmaxf(t, 0.f));

  for (int e = 0; e < need; ++e) {
    int mn = myNext;
#pragma unroll
    for (int off = 32; off > 0; off >>= 1) mn = min(mn, __shfl_xor(mn, off));
    if (myNext == mn) {              // unique owner (index sets disjoint mod 64)
      float px, py, pz;
      if (S3) { px = P3[3*mn]; py = P3[3*mn+1]; pz = P3[3*mn+2]; }
      else    { float4 f = P4[mn]; px = f.x; py = f.y; pz = f.z; }
      sx += px; sy += py; sz += pz; sr += rt;
      int nx = 0x7fffffff;
      for (int j = (mn - lane) / 64 + 1; j < CH; ++j) {
        int p = lane + 64 * j;
        float ux, uy, uz;
        if (S3) { ux = P3[3*p]; uy = P3[3*p+1]; uz = P3[3*p+2]; }
        else    { float4 f = P4[p]; ux = f.x; uy = f.y; uz = f.z; }
        float d = d2gram(ux, uy, uz, q.x, q.y, q.z, q2);
        if (d == t) { nx = p; break; }
      }
      myNext = nx;
    }
  }

#pragma unroll
  for (int off = 32; off > 0; off >>= 1) {
    sx += __shfl_xor(sx, off);
    sy += __shfl_xor(sy, off);
    sz += __shfl_xor(sz, off);
    sr += __shfl_xor(sr, off);
  }
  if (lane == 0) {
    const float inv = 1.0f / (float)K;
    outc[qid] = make_float4(sx * inv, sy * inv, sz * inv, 0.f);
    outr[qid] = sr * inv;
  }
}

// ---------------------------------------------------------------------------
__global__ void gather1_kernel(const float* __restrict__ xyz,
                               const int* __restrict__ ids,
                               float4* __restrict__ cen)
{
  int g = blockIdx.x * 256 + threadIdx.x;
  if (g >= BATCH * M1) return;
  int b = g / M1;
  size_t base = ((size_t)b * NPTS + ids[g]) * 3;
  cen[g] = make_float4(xyz[base], xyz[base+1], xyz[base+2], 0.f);
}

__global__ void gather2_kernel(const float4* __restrict__ cen4,
                               const float* __restrict__ rad1,
                               const int* __restrict__ ids2,
                               float4* __restrict__ cen2,
                               float* __restrict__ radg)
{
  int g = blockIdx.x * 256 + threadIdx.x;
  if (g >= BATCH * SKP) return;
  int b = g / SKP;
  int p = ids2[g];
  cen2[g] = cen4[(size_t)b * M1 + p];
  radg[g] = rad1[(size_t)b * M1 + p];
}

__global__ void finalize_kernel(const float4* __restrict__ cen,
                                const float* __restrict__ radg,
                                const float* __restrict__ rad2,
                                const float* __restrict__ tmpl,
                                float* __restrict__ out)
{
  int g = blockIdx.x * 256 + threadIdx.x;
  int s = g >> 7;
  int j = g & 127;
  float4 c = cen[s];
  float r = __fmul_rn(__fadd_rn(radg[s], rad2[s]), 1.5f);
  float tx = tmpl[3*j], ty = tmpl[3*j+1], tz = tmpl[3*j+2];
  float* sp = out + BATCH * SKP * 3;
  sp[3*g]     = __fadd_rn(c.x, __fmul_rn(r, tx));
  sp[3*g + 1] = __fadd_rn(c.y, __fmul_rn(r, ty));
  sp[3*g + 2] = __fadd_rn(c.z, __fmul_rn(r, tz));
  if (j == 0) {
    out[3*s] = c.x; out[3*s+1] = c.y; out[3*s+2] = c.z;
    out[BATCH*SKP*3 + BATCH*SKP*SPHN*3 + s] = r;
  }
}

// ---------------------------------------------------------------------------
extern "C" void kernel_launch(void* const* d_in, const int* in_sizes, int n_in,
                              void* d_out, int out_size, void* d_ws, size_t ws_size,
                              hipStream_t stream)
{
  const float* xyz  = (const float*)d_in[0];   // f32 [B, N, 3]
  const float* tmpl = (const float*)d_in[1];   // f32 [128, 3]
  float* out = (float*)d_out;                  // f32 outputs
  char* ws = (char*)d_ws;

  // total ws footprint: 418,048 B
  int*    ids1  = (int*)   (ws + 0);        //  32768 B
  float4* cen4a = (float4*)(ws + 32768);    // 131072 B
  float4* cen4b = (float4*)(ws + 163840);   // 131072 B
  float*  rad1  = (float*) (ws + 294912);   //  32768 B
  int*    ids2  = (int*)   (ws + 327680);   //   8192 B
  float4* cen2a = (float4*)(ws + 335872);   //  32768 B
  float4* cen2b = (float4*)(ws + 368640);   //  32768 B
  float*  radg  = (float*) (ws + 401408);   //   8192 B
  float*  rad2  = (float*) (ws + 409600);   //   8192 B
  unsigned long long* sync = (unsigned long long*)(ws + 417792); // 256 B

  // Stage 1: FPS to 2048 seeds per batch (4 blocks per batch, atomic handshake)
  fps1_kernel<<<BATCH * 4, 1024, 0, stream>>>(xyz, ids1, sync);
  gather1_kernel<<<(BATCH * M1 + 255) / 256, 256, 0, stream>>>(xyz, ids1, cen4a);
  // two skeletonization passes, k=32 (fast per-lane top-8 + exact fallback)
  sklnz_kernel<KA, 8, NPTS, true><<<BATCH * M1 / 4, 256, 0, stream>>>(cen4a, xyz, cen4b, rad1, M1);
  sklnz_kernel<KA, 8, NPTS, true><<<BATCH * M1 / 4, 256, 0, stream>>>(cen4b, xyz, cen4a, rad1, M1);
  // Stage 2: FPS 2048 -> 512 on intermediate skeleton (cen4a)
  fps2_kernel<<<BATCH, 256, 0, stream>>>(cen4a, ids2);
  gather2_kernel<<<(BATCH * SKP + 255) / 256, 256, 0, stream>>>(cen4a, rad1, ids2, cen2a, radg);
  // two skeletonization passes, k=2 (KL == K -> exact, no fallback)
  sklnz_kernel<KB, KB, M1, false><<<BATCH * SKP / 4, 256, 0, stream>>>(cen2a, cen4a, cen2b, rad2, SKP);
  sklnz_kernel<KB, KB, M1, false><<<BATCH * SKP / 4, 256, 0, stream>>>(cen2b, cen4a, cen2a, rad2, SKP);
  // Outputs: centers, sphere points, radii (f32)
  finalize_kernel<<<BATCH * SKP * SPHN / 256, 256, 0, stream>>>(cen2a, radg, rad2, tmpl, out);
}

// Round 14
// 7453.237 us; speedup vs baseline: 3.0182x; 1.0120x over previous
//
#include <hip/hip_runtime.h>
#include <cstdint>

#define BATCH 4
#define NPTS  32768
#define QN    8192            /* points per fps1 block (4 blocks per batch) */
#define SKP   512
#define M1    (SKP*4)   /* 2048 */
#define KA    32
#define KB    2
#define SPHN  128

// FPS distance: reference _fps uses sum((x-c)**2) = ((dx*dx+dy*dy)+dz*dz),
// pinned round-to-nearest, NO fma contraction (bitwise == numpy).
__device__ __forceinline__ float sqdist(float px, float py, float pz,
                                        float cx, float cy, float cz) {
  float dx = px - cx, dy = py - cy, dz = pz - cz;
  return __fadd_rn(__fadd_rn(__fmul_rn(dx, dx), __fmul_rn(dy, dy)),
                   __fmul_rn(dz, dz));
}
// sklnz distance: reference _pairwise_sqdist uses c2 + p2 - 2*cp (Gram form).
__device__ __forceinline__ float d2gram(float px, float py, float pz,
                                        float qx, float qy, float qz, float q2) {
  float p2 = __fadd_rn(__fadd_rn(__fmul_rn(px, px), __fmul_rn(py, py)),
                       __fmul_rn(pz, pz));
  float cp = __fadd_rn(__fadd_rn(__fmul_rn(qx, px), __fmul_rn(qy, py)),
                       __fmul_rn(qz, pz));
  return __fsub_rn(__fadd_rn(q2, p2), __fadd_rn(cp, cp));
}

// ---------------------------------------------------------------------------
// Stage-1 FPS, 4 blocks per batch. xy in LDS (64KB), z[8]+dist[8] in VGPRs.
// Handshake: RELAXED agent-scope 64-bit atomics. R13 used acquire/release,
// which on gfx950 emit L1/L2 invalidations per poll and writeback fences per
// store -- but this protocol needs NO fences: the whole message
// (value|idx|tag) is inside the one atomic word, pivot coords come from the
// never-written input X, and ids[] ordering is covered by the kernel
// boundary. Agent scope alone guarantees LLC-level visibility.
// Payload = valueBits<<32 | idx<<12 | it; parity-indexed slot pairs; poison
// tag 0xAAA > 2047 never matches; cross-replay stale matches are
// bit-identical by determinism (benign). Tie-break: greater wins, equal ->
// smaller global index (jnp.argmax first-occurrence).
// ---------------------------------------------------------------------------
__global__ __launch_bounds__(1024)
void fps1_kernel(const float* __restrict__ xyz, int* __restrict__ ids,
                 unsigned long long* __restrict__ sync)
{
  int blk = blockIdx.x;
  int b = blk >> 2, sub = blk & 3;
  const float* X = xyz + (size_t)b * NPTS * 3;
  ids += (size_t)b * M1;
  int tid = threadIdx.x, lane = tid & 63, wave = tid >> 6;
  int base = sub * QN;

  __shared__ float2 xysh[QN];          // 65536 B
  __shared__ float s_v[16];
  __shared__ int   s_i[16];
  __shared__ float s_piv[3];

  float zr[8], dist[8];
#pragma unroll
  for (int j = 0; j < 8; ++j) {
    int pl = tid + 1024 * j;
    int pg = base + pl;
    xysh[pl] = make_float2(X[3*pg], X[3*pg+1]);
    zr[j] = X[3*pg+2];
    dist[j] = 1e10f;
  }
  __syncthreads();

  if (sub == 0 && tid == 0) ids[0] = 0;
  float cx = X[0], cy = X[1], cz = X[2];

  for (int it = 1; it < M1; ++it) {
    float best = -1.f; int besti = 0;
#pragma unroll
    for (int j = 0; j < 8; ++j) {
      int pl = tid + 1024 * j;
      float2 c2 = xysh[pl];
      float d = sqdist(c2.x, c2.y, zr[j], cx, cy, cz);
      d = fminf(dist[j], d);
      dist[j] = d;
      bool gt = d > best;
      best  = gt ? d : best;
      besti = gt ? (base + pl) : besti;
    }
    // wave argmax (tie -> smaller index)
#pragma unroll
    for (int off = 32; off > 0; off >>= 1) {
      float ov = __shfl_xor(best, off);
      int   oi = __shfl_xor(besti, off);
      if (ov > best || (ov == best && oi < besti)) { best = ov; besti = oi; }
    }
    if (lane == 0) { s_v[wave] = best; s_i[wave] = besti; }
    __syncthreads();                       // barrier 1
    if (wave == 0) {
      float v = -1.f; int i = 0x7fffffff;
      if (lane < 16) { v = s_v[lane]; i = s_i[lane]; }
#pragma unroll
      for (int off = 8; off > 0; off >>= 1) {
        float ov = __shfl_xor(v, off);
        int   oi = __shfl_xor(i, off);
        if (ov > v || (ov == v && oi < i)) { v = ov; i = oi; }
      }
      v = __shfl(v, 0); i = __shfl(i, 0);  // block winner -> all lanes
      unsigned long long packed =
          ((unsigned long long)__float_as_uint(v) << 32) |
          ((unsigned)i << 12) | (unsigned)it;
      int si = b * 8 + (it & 1) * 4;
      if (lane == 0)
        __hip_atomic_store(&sync[si + sub], packed,
                           __ATOMIC_RELAXED, __HIP_MEMORY_SCOPE_AGENT);
      unsigned long long rp = packed;      // lanes 1..3 poll remote slots
      if (lane >= 1 && lane <= 3) {
        int rs = si + ((sub + lane) & 3);
        do {
          rp = __hip_atomic_load(&sync[rs],
                                 __ATOMIC_RELAXED, __HIP_MEMORY_SCOPE_AGENT);
        } while ((unsigned)(rp & 0xFFFu) != (unsigned)it);
      }
      float cv = __uint_as_float((unsigned)(rp >> 32));
      int   ci = (int)((rp >> 12) & 0x7FFFu);
      // reduce candidates over lanes 0..3 (higher lanes reduce duplicates)
#pragma unroll
      for (int off = 2; off > 0; off >>= 1) {
        float ov = __shfl_xor(cv, off);
        int   oi = __shfl_xor(ci, off);
        if (ov > cv || (ov == cv && oi < ci)) { cv = ov; ci = oi; }
      }
      ci = __shfl(ci, 0);
      if (lane == 0 && sub == 0) ids[it] = ci;
      if (lane < 3) s_piv[lane] = X[3 * ci + lane];
    }
    __syncthreads();                       // barrier 2
    cx = s_piv[0]; cy = s_piv[1]; cz = s_piv[2];
  }
}

// ---------------------------------------------------------------------------
// Stage-2 FPS on the 2048-pt intermediate skeleton, LDS-staged (32KB).
// ---------------------------------------------------------------------------
__global__ __launch_bounds__(256)
void fps2_kernel(const float4* __restrict__ pts, int* __restrict__ ids)
{
  const int PTS = 8, BLOCK = 256, NW = 4;
  int b = blockIdx.x;
  pts += (size_t)b * M1;
  ids += (size_t)b * SKP;
  int tid = threadIdx.x, lane = tid & 63, wave = tid >> 6;

  __shared__ float4 pl[M1];            // 32768 B
  __shared__ float s_v[2][NW];
  __shared__ int   s_i[2][NW];

  float dist[PTS];
#pragma unroll
  for (int j = 0; j < PTS; ++j) {
    int p = tid + BLOCK * j;
    pl[p] = pts[p];
    dist[j] = 1e10f;
  }
  __syncthreads();

  if (tid == 0) ids[0] = 0;
  float4 piv = pl[0];
  float cx = piv.x, cy = piv.y, cz = piv.z;

  for (int it = 1; it < SKP; ++it) {
    float best = -1.f; int besti = 0;
#pragma unroll
    for (int j = 0; j < PTS; ++j) {
      int p = tid + BLOCK * j;
      float4 f = pl[p];
      float d = sqdist(f.x, f.y, f.z, cx, cy, cz);
      d = fminf(dist[j], d);
      dist[j] = d;
      bool gt = d > best;
      best  = gt ? d : best;
      besti = gt ? p : besti;
    }
#pragma unroll
    for (int off = 32; off > 0; off >>= 1) {
      float ov = __shfl_xor(best, off);
      int   oi = __shfl_xor(besti, off);
      if (ov > best || (ov == best && oi < besti)) { best = ov; besti = oi; }
    }
    int par = it & 1;
    if (lane == 0) { s_v[par][wave] = best; s_i[par][wave] = besti; }
    __syncthreads();
    float v = -1.f; int i = 0x7fffffff;
    if (lane < NW) { v = s_v[par][lane]; i = s_i[par][lane]; }
#pragma unroll
    for (int off = NW >> 1; off > 0; off >>= 1) {
      float ov = __shfl_xor(v, off);
      int   oi = __shfl_xor(i, off);
      if (ov > v || (ov == v && oi < i)) { v = ov; i = oi; }
    }
    i = __shfl(i, 0);
    if (tid == 0) ids[it] = i;
    float4 pv = pl[i];
    cx = pv.x; cy = pv.y; cz = pv.z;
  }
}

// ---------------------------------------------------------------------------
// Skeletonization: wave per query, GRAM-form distances.
// Fast path: per-lane sorted top-KL (KL=8 for K=32), heads-merge K rounds
// -> t. Subset argument: t >= t_true always; rescan counts strict-less over
// ALL points, so ctot >= K detects t > t_true exactly -> rare fallback
// recomputes with full per-lane top-K. Tie-fill (exact lax.top_k semantics)
// runs on the verified t.
// ---------------------------------------------------------------------------
template<int K, int KL, int N, bool S3>
__global__ __launch_bounds__(256)
void sklnz_kernel(const float4* __restrict__ queries,
                  const void*   __restrict__ ptsv,
                  float4* __restrict__ outc,
                  float*  __restrict__ outr,
                  int M)
{
  const int CH = N / 64;
  int wave = threadIdx.x >> 6, lane = threadIdx.x & 63;
  int qid = blockIdx.x * 4 + wave;
  int b = qid / M;
  const float*  P3 = (const float*)ptsv + (size_t)b * N * 3;
  const float4* P4 = (const float4*)ptsv + (size_t)b * N;
  float4 q = queries[qid];
  float q2 = __fadd_rn(__fadd_rn(__fmul_rn(q.x, q.x), __fmul_rn(q.y, q.y)),
                       __fmul_rn(q.z, q.z));

  __shared__ float heads[4][64][K + 1];

  // ---- fast scan: per-lane sorted top-KL ----
  float a[KL];
#pragma unroll
  for (int s = 0; s < KL; ++s) a[s] = 3.0e38f;
  for (int j = 0; j < CH; ++j) {
    int p = lane + 64 * j;
    float px, py, pz;
    if (S3) { px = P3[3*p]; py = P3[3*p+1]; pz = P3[3*p+2]; }
    else    { float4 f = P4[p]; px = f.x; py = f.y; pz = f.z; }
    float d = d2gram(px, py, pz, q.x, q.y, q.z, q2);
#pragma unroll
    for (int s = KL - 1; s > 0; --s) a[s] = fminf(a[s], fmaxf(a[s-1], d));
    a[0] = fminf(a[0], d);
  }
  // ---- merge: K rounds over per-lane lists (sentinel-terminated) ----
#pragma unroll
  for (int s = 0; s < KL; ++s) heads[wave][lane][s] = a[s];
  heads[wave][lane][KL] = 3.1e38f;
  int h = 0; float t = 0.f;
  for (int r = 0; r < K; ++r) {
    float mv = heads[wave][lane][h];
    int   ml = lane;
#pragma unroll
    for (int off = 32; off > 0; off >>= 1) {
      float ov = __shfl_xor(mv, off);
      int   ol = __shfl_xor(ml, off);
      if (ov < mv || (ov == mv && ol < ml)) { mv = ov; ml = ol; }
    }
    t = mv;
    if (ml == lane) h++;
  }

  // ---- rescan: accumulate d < t, count, per-lane first d == t ----
  float sx = 0.f, sy = 0.f, sz = 0.f, sr = 0.f;
  int cl = 0;
  int myNext = 0x7fffffff;
  for (int j = 0; j < CH; ++j) {
    int p = lane + 64 * j;
    float px, py, pz;
    if (S3) { px = P3[3*p]; py = P3[3*p+1]; pz = P3[3*p+2]; }
    else    { float4 f = P4[p]; px = f.x; py = f.y; pz = f.z; }
    float d = d2gram(px, py, pz, q.x, q.y, q.z, q2);
    if (d < t) { sx += px; sy += py; sz += pz; sr += sqrtf(fmaxf(d, 0.f)); cl++; }
    else if (d == t && myNext == 0x7fffffff) myNext = p;
  }
  int ctot = cl;
#pragma unroll
  for (int off = 32; off > 0; off >>= 1) ctot += __shfl_xor(ctot, off);

  if constexpr (KL < K) {
    if (ctot >= K) {
      // ---- exact fallback: full per-lane top-K (rare) ----
      float a2[K];
#pragma unroll
      for (int s = 0; s < K; ++s) a2[s] = 3.0e38f;
      for (int j = 0; j < CH; ++j) {
        int p = lane + 64 * j;
        float px, py, pz;
        if (S3) { px = P3[3*p]; py = P3[3*p+1]; pz = P3[3*p+2]; }
        else    { float4 f = P4[p]; px = f.x; py = f.y; pz = f.z; }
        float d = d2gram(px, py, pz, q.x, q.y, q.z, q2);
#pragma unroll
        for (int s = K - 1; s > 0; --s) a2[s] = fminf(a2[s], fmaxf(a2[s-1], d));
        a2[0] = fminf(a2[0], d);
      }
#pragma unroll
      for (int s = 0; s < K; ++s) heads[wave][lane][s] = a2[s];
      heads[wave][lane][K] = 3.1e38f;
      h = 0;
      for (int r = 0; r < K; ++r) {
        float mv = heads[wave][lane][h];
        int   ml = lane;
#pragma unroll
        for (int off = 32; off > 0; off >>= 1) {
          float ov = __shfl_xor(mv, off);
          int   ol = __shfl_xor(ml, off);
          if (ov < mv || (ov == mv && ol < ml)) { mv = ov; ml = ol; }
        }
        t = mv;
        if (ml == lane) h++;
      }
      sx = sy = sz = sr = 0.f; cl = 0; myNext = 0x7fffffff;
      for (int j = 0; j < CH; ++j) {
        int p = lane + 64 * j;
        float px, py, pz;
        if (S3) { px = P3[3*p]; py = P3[3*p+1]; pz = P3[3*p+2]; }
        else    { float4 f = P4[p]; px = f.x; py = f.y; pz = f.z; }
        float d = d2gram(px, py, pz, q.x, q.y, q.z, q2);
        if (d < t) { sx += px; sy += py; sz += pz; sr += sqrtf(fmaxf(d, 0.f)); cl++; }
        else if (d == t && myNext == 0x7fffffff) myNext = p;
      }
      ctot = cl;
#pragma unroll
      for (int off = 32; off > 0; off >>= 1) ctot += __shfl_xor(ctot, off);
    }
  }

  int need = K - ctot;               // >= 1, <= multiplicity of t
  float rt = sqrtf(fmaxf(t, 0.f));

  for (int e = 0; e < need; ++e) {
    int mn = myNext;
#pragma unroll
    for (int off = 32; off > 0; off >>= 1) mn = min(mn, __shfl_xor(mn, off));
    if (myNext == mn) {              // unique owner (index sets disjoint mod 64)
      float px, py, pz;
      if (S3) { px = P3[3*mn]; py = P3[3*mn+1]; pz = P3[3*mn+2]; }
      else    { float4 f = P4[mn]; px = f.x; py = f.y; pz = f.z; }
      sx += px; sy += py; sz += pz; sr += rt;
      int nx = 0x7fffffff;
      for (int j = (mn - lane) / 64 + 1; j < CH; ++j) {
        int p = lane + 64 * j;
        float ux, uy, uz;
        if (S3) { ux = P3[3*p]; uy = P3[3*p+1]; uz = P3[3*p+2]; }
        else    { float4 f = P4[p]; ux = f.x; uy = f.y; uz = f.z; }
        float d = d2gram(ux, uy, uz, q.x, q.y, q.z, q2);
        if (d == t) { nx = p; break; }
      }
      myNext = nx;
    }
  }

#pragma unroll
  for (int off = 32; off > 0; off >>= 1) {
    sx += __shfl_xor(sx, off);
    sy += __shfl_xor(sy, off);
    sz += __shfl_xor(sz, off);
    sr += __shfl_xor(sr, off);
  }
  if (lane == 0) {
    const float inv = 1.0f / (float)K;
    outc[qid] = make_float4(sx * inv, sy * inv, sz * inv, 0.f);
    outr[qid] = sr * inv;
  }
}

// ---------------------------------------------------------------------------
__global__ void gather1_kernel(const float* __restrict__ xyz,
                               const int* __restrict__ ids,
                               float4* __restrict__ cen)
{
  int g = blockIdx.x * 256 + threadIdx.x;
  if (g >= BATCH * M1) return;
  int b = g / M1;
  size_t base = ((size_t)b * NPTS + ids[g]) * 3;
  cen[g] = make_float4(xyz[base], xyz[base+1], xyz[base+2], 0.f);
}

__global__ void gather2_kernel(const float4* __restrict__ cen4,
                               const float* __restrict__ rad1,
                               const int* __restrict__ ids2,
                               float4* __restrict__ cen2,
                               float* __restrict__ radg)
{
  int g = blockIdx.x * 256 + threadIdx.x;
  if (g >= BATCH * SKP) return;
  int b = g / SKP;
  int p = ids2[g];
  cen2[g] = cen4[(size_t)b * M1 + p];
  radg[g] = rad1[(size_t)b * M1 + p];
}

__global__ void finalize_kernel(const float4* __restrict__ cen,
                                const float* __restrict__ radg,
                                const float* __restrict__ rad2,
                                const float* __restrict__ tmpl,
                                float* __restrict__ out)
{
  int g = blockIdx.x * 256 + threadIdx.x;
  int s = g >> 7;
  int j = g & 127;
  float4 c = cen[s];
  float r = __fmul_rn(__fadd_rn(radg[s], rad2[s]), 1.5f);
  float tx = tmpl[3*j], ty = tmpl[3*j+1], tz = tmpl[3*j+2];
  float* sp = out + BATCH * SKP * 3;
  sp[3*g]     = __fadd_rn(c.x, __fmul_rn(r, tx));
  sp[3*g + 1] = __fadd_rn(c.y, __fmul_rn(r, ty));
  sp[3*g + 2] = __fadd_rn(c.z, __fmul_rn(r, tz));
  if (j == 0) {
    out[3*s] = c.x; out[3*s+1] = c.y; out[3*s+2] = c.z;
    out[BATCH*SKP*3 + BATCH*SKP*SPHN*3 + s] = r;
  }
}

// ---------------------------------------------------------------------------
extern "C" void kernel_launch(void* const* d_in, const int* in_sizes, int n_in,
                              void* d_out, int out_size, void* d_ws, size_t ws_size,
                              hipStream_t stream)
{
  const float* xyz  = (const float*)d_in[0];   // f32 [B, N, 3]
  const float* tmpl = (const float*)d_in[1];   // f32 [128, 3]
  float* out = (float*)d_out;                  // f32 outputs
  char* ws = (char*)d_ws;

  // total ws footprint: 418,048 B
  int*    ids1  = (int*)   (ws + 0);        //  32768 B
  float4* cen4a = (float4*)(ws + 32768);    // 131072 B
  float4* cen4b = (float4*)(ws + 163840);   // 131072 B
  float*  rad1  = (float*) (ws + 294912);   //  32768 B
  int*    ids2  = (int*)   (ws + 327680);   //   8192 B
  float4* cen2a = (float4*)(ws + 335872);   //  32768 B
  float4* cen2b = (float4*)(ws + 368640);   //  32768 B
  float*  radg  = (float*) (ws + 401408);   //   8192 B
  float*  rad2  = (float*) (ws + 409600);   //   8192 B
  unsigned long long* sync = (unsigned long long*)(ws + 417792); // 256 B

  // Stage 1: FPS to 2048 seeds per batch (4 blocks per batch, relaxed atomics)
  fps1_kernel<<<BATCH * 4, 1024, 0, stream>>>(xyz, ids1, sync);
  gather1_kernel<<<(BATCH * M1 + 255) / 256, 256, 0, stream>>>(xyz, ids1, cen4a);
  // two skeletonization passes, k=32 (fast per-lane top-8 + exact fallback)
  sklnz_kernel<KA, 8, NPTS, true><<<BATCH * M1 / 4, 256, 0, stream>>>(cen4a, xyz, cen4b, rad1, M1);
  sklnz_kernel<KA, 8, NPTS, true><<<BATCH * M1 / 4, 256, 0, stream>>>(cen4b, xyz, cen4a, rad1, M1);
  // Stage 2: FPS 2048 -> 512 on intermediate skeleton (cen4a)
  fps2_kernel<<<BATCH, 256, 0, stream>>>(cen4a, ids2);
  gather2_kernel<<<(BATCH * SKP + 255) / 256, 256, 0, stream>>>(cen4a, rad1, ids2, cen2a, radg);
  // two skeletonization passes, k=2 (KL == K -> exact, no fallback)
  sklnz_kernel<KB, KB, M1, false><<<BATCH * SKP / 4, 256, 0, stream>>>(cen2a, cen4a, cen2b, rad2, SKP);
  sklnz_kernel<KB, KB, M1, false><<<BATCH * SKP / 4, 256, 0, stream>>>(cen2b, cen4a, cen2a, rad2, SKP);
  // Outputs: centers, sphere points, radii (f32)
  finalize_kernel<<<BATCH * SKP * SPHN / 256, 256, 0, stream>>>(cen2a, radg, rad2, tmpl, out);
}

// Round 15
// 4413.197 us; speedup vs baseline: 5.0972x; 1.6889x over previous
//
#include <hip/hip_runtime.h>
#include <cstdint>

#define BATCH 4
#define NPTS  32768
#define QN    8192            /* points per fps1 block (4 blocks per batch) */
#define SKP   512
#define M1    (SKP*4)   /* 2048 */
#define KA    32
#define KB    2
#define SPHN  128

// FPS distance: reference _fps uses sum((x-c)**2) = ((dx*dx+dy*dy)+dz*dz),
// pinned round-to-nearest, NO fma contraction (bitwise == numpy).
__device__ __forceinline__ float sqdist(float px, float py, float pz,
                                        float cx, float cy, float cz) {
  float dx = px - cx, dy = py - cy, dz = pz - cz;
  return __fadd_rn(__fadd_rn(__fmul_rn(dx, dx), __fmul_rn(dy, dy)),
                   __fmul_rn(dz, dz));
}
// sklnz distance: reference _pairwise_sqdist uses c2 + p2 - 2*cp (Gram form).
__device__ __forceinline__ float d2gram(float px, float py, float pz,
                                        float qx, float qy, float qz, float q2) {
  float p2 = __fadd_rn(__fadd_rn(__fmul_rn(px, px), __fmul_rn(py, py)),
                       __fmul_rn(pz, pz));
  float cp = __fadd_rn(__fadd_rn(__fmul_rn(qx, px), __fmul_rn(qy, py)),
                       __fmul_rn(qz, pz));
  return __fsub_rn(__fadd_rn(q2, p2), __fadd_rn(cp, cp));
}

__device__ __forceinline__ unsigned long long shfl_xor_u64(unsigned long long v, int off) {
  int lo = __shfl_xor((int)(unsigned)v, off);
  int hi = __shfl_xor((int)(unsigned)(v >> 32), off);
  return ((unsigned long long)(unsigned)hi << 32) | (unsigned)lo;
}
__device__ __forceinline__ unsigned long long shfl_u64(unsigned long long v, int src) {
  int lo = __shfl((int)(unsigned)v, src);
  int hi = __shfl((int)(unsigned)(v >> 32), src);
  return ((unsigned long long)(unsigned)hi << 32) | (unsigned)lo;
}

// ---------------------------------------------------------------------------
// Stage-1 FPS, batched-candidate exact algorithm. 4 blocks/batch, xy in LDS,
// z[8]+dist[8] in VGPRs. Per super-round: multi-pivot scan, per-thread top-2
// KEYS (key = distBits<<15 | 0x7FFF-idx : value desc, index asc == jnp.argmax
// order), wave top-2 merge, block publishes 16 wave-top1 keys + floor (max of
// wave-top2s) via relaxed agent-scope atomics (tag=rc, parity banks, poison
// 0xAAA=2730 > max rc 2047, cross-replay stale == fresh by determinism).
// All blocks redundantly simulate picks from the 64-candidate union while
// unionMaxKey > floorKey: every non-candidate key <= floor and only
// decreases, so each pick is the exact global argmax; keys unique (index
// embedded) => first pick always strict => progress guaranteed. Picked
// pivots (<=16) applied to dist[] next scan, idempotent-padded chunks of 4.
// ---------------------------------------------------------------------------
__global__ __launch_bounds__(1024)
void fps1_kernel(const float* __restrict__ xyz, int* __restrict__ ids,
                 unsigned long long* __restrict__ sync)
{
  int blk = blockIdx.x;
  int b = blk >> 2, sub = blk & 3;
  const float* X = xyz + (size_t)b * NPTS * 3;
  ids += (size_t)b * M1;
  int tid = threadIdx.x, lane = tid & 63, wave = tid >> 6;
  int base = sub * QN;

  __shared__ float2 xysh[QN];               // 65536 B
  __shared__ unsigned long long s_w[16][2]; // per-wave top-2 keys
  __shared__ float s_pivc[16][3];
  __shared__ int s_J;

  float zr[8], dist[8];
#pragma unroll
  for (int j = 0; j < 8; ++j) {
    int pl = tid + 1024 * j;
    int pg = base + pl;
    xysh[pl] = make_float2(X[3*pg], X[3*pg+1]);
    zr[j] = X[3*pg+2];
    dist[j] = 1e10f;
  }
  if (tid == 0) {
    s_pivc[0][0] = X[0]; s_pivc[0][1] = X[1]; s_pivc[0][2] = X[2];
    if (sub == 0) ids[0] = 0;
  }
  __syncthreads();

  int it = 1, J = 1, rc = 1;

  while (it < M1) {
    // ---- scan: apply J pivots in idempotent-padded chunks of 4 ----
    for (int jp0 = 0; jp0 < J; jp0 += 4) {
      float pxa[4], pya[4], pza[4];
#pragma unroll
      for (int l = 0; l < 4; ++l) {
        int jj = jp0 + l; jj = (jj < J) ? jj : jp0;   // re-apply is harmless (min)
        pxa[l] = s_pivc[jj][0]; pya[l] = s_pivc[jj][1]; pza[l] = s_pivc[jj][2];
      }
#pragma unroll
      for (int j = 0; j < 8; ++j) {
        int pl = tid + 1024 * j;
        float2 c2 = xysh[pl];
        float dd = dist[j];
#pragma unroll
        for (int l = 0; l < 4; ++l)
          dd = fminf(dd, sqdist(c2.x, c2.y, zr[j], pxa[l], pya[l], pza[l]));
        dist[j] = dd;
      }
    }
    // ---- per-thread top-2 keys ----
    unsigned long long k1 = 0, k2 = 0;
#pragma unroll
    for (int j = 0; j < 8; ++j) {
      int pg = base + tid + 1024 * j;
      unsigned long long key =
          ((unsigned long long)__float_as_uint(dist[j]) << 15) |
          (unsigned)(0x7FFF - pg);
      if (key > k1) { k2 = k1; k1 = key; }
      else if (key > k2) { k2 = key; }
    }
    // ---- wave top-2 merge (sorted-pair merge) ----
#pragma unroll
    for (int off = 32; off > 0; off >>= 1) {
      unsigned long long o1 = shfl_xor_u64(k1, off);
      unsigned long long o2 = shfl_xor_u64(k2, off);
      if (o1 > k1) { unsigned long long t = k1; k1 = o1; k2 = (t > o2) ? t : o2; }
      else         { k2 = (k2 > o1) ? k2 : o1; }
    }
    if (lane == 0) { s_w[wave][0] = k1; s_w[wave][1] = k2; }
    __syncthreads();                       // barrier A
    if (wave == 0) {
      unsigned long long c1 = 0, c2v = 0;
      if (lane < 16) { c1 = s_w[lane][0]; c2v = s_w[lane][1]; }
      unsigned long long fb = c2v;         // block floor = max of wave-2nds
#pragma unroll
      for (int off = 8; off > 0; off >>= 1) {
        unsigned long long o = shfl_xor_u64(fb, off);
        if (o > fb) fb = o;
      }
      fb = shfl_u64(fb, 0);
      unsigned tag = (unsigned)rc;
      int par = rc & 1;
      int sbase = ((b * 2 + par) * 4 + sub) * 20;
      if (lane < 16)
        __hip_atomic_store(&sync[sbase + lane], (c1 << 12) | tag,
                           __ATOMIC_RELAXED, __HIP_MEMORY_SCOPE_AGENT);
      if (lane == 0)
        __hip_atomic_store(&sync[sbase + 16], (fb << 12) | tag,
                           __ATOMIC_RELAXED, __HIP_MEMORY_SCOPE_AGENT);
      // poll 48 remote candidates (lanes 16-63) + 3 remote floors (lanes 1-3)
      unsigned long long ck = c1;          // lanes 0..15: own candidates
      unsigned long long rfk = 0;
      int cslot = 0, fslot = 0;
      bool needc = (lane >= 16), needf = (lane >= 1 && lane <= 3);
      if (needc) {
        int rsub = (sub + (lane >> 4)) & 3;
        cslot = ((b * 2 + par) * 4 + rsub) * 20 + (lane & 15);
      }
      if (needf) {
        int rsub = (sub + lane) & 3;
        fslot = ((b * 2 + par) * 4 + rsub) * 20 + 16;
      }
      while (__any(needc || needf)) {
        if (needc) {
          unsigned long long v = __hip_atomic_load(&sync[cslot],
                                  __ATOMIC_RELAXED, __HIP_MEMORY_SCOPE_AGENT);
          if ((unsigned)(v & 0xFFFu) == tag) { ck = v >> 12; needc = false; }
        }
        if (needf) {
          unsigned long long v = __hip_atomic_load(&sync[fslot],
                                  __ATOMIC_RELAXED, __HIP_MEMORY_SCOPE_AGENT);
          if ((unsigned)(v & 0xFFFu) == tag) { rfk = v >> 12; needf = false; }
        }
      }
      unsigned long long f = fb;
      unsigned long long f1 = shfl_u64(rfk, 1);
      unsigned long long f2 = shfl_u64(rfk, 2);
      unsigned long long f3 = shfl_u64(rfk, 3);
      if (f1 > f) f = f1;
      if (f2 > f) f = f2;
      if (f3 > f) f = f3;
      // candidate coords (one candidate per lane, 64 total)
      int ci = 0x7FFF - (int)(ck & 0x7FFFu);
      float cx = X[3*ci], cy = X[3*ci+1], cz = X[3*ci+2];
      int Jn = 0;
      while (it + Jn < M1 && Jn < 16) {
        unsigned long long mk = ck;
#pragma unroll
        for (int off = 32; off > 0; off >>= 1) {
          unsigned long long o = shfl_xor_u64(mk, off);
          if (o > mk) mk = o;
        }
        if (!(mk > f)) break;              // outside point could tie -> exchange
        unsigned long long ball = __ballot(ck == mk);   // unique (keys unique)
        int wl = __ffsll(ball) - 1;
        float px = __shfl(cx, wl), py = __shfl(cy, wl), pz = __shfl(cz, wl);
        if (lane == 0) {
          s_pivc[Jn][0] = px; s_pivc[Jn][1] = py; s_pivc[Jn][2] = pz;
          if (sub == 0) ids[it + Jn] = 0x7FFF - (int)(mk & 0x7FFFu);
        }
        float d = sqdist(cx, cy, cz, px, py, pz);
        float nv = fminf(__uint_as_float((unsigned)(ck >> 15)), d);
        ck = ((unsigned long long)__float_as_uint(nv) << 15) | (ck & 0x7FFFu);
        ++Jn;
      }
      if (lane == 0) s_J = Jn;
    }
    __syncthreads();                       // barrier B
    J = s_J;
    it += J;
    rc += 1;
  }
}

// ---------------------------------------------------------------------------
// Stage-2 FPS on the 2048-pt intermediate skeleton, LDS-staged (32KB).
// ---------------------------------------------------------------------------
__global__ __launch_bounds__(256)
void fps2_kernel(const float4* __restrict__ pts, int* __restrict__ ids)
{
  const int PTS = 8, BLOCK = 256, NW = 4;
  int b = blockIdx.x;
  pts += (size_t)b * M1;
  ids += (size_t)b * SKP;
  int tid = threadIdx.x, lane = tid & 63, wave = tid >> 6;

  __shared__ float4 pl[M1];            // 32768 B
  __shared__ float s_v[2][NW];
  __shared__ int   s_i[2][NW];

  float dist[PTS];
#pragma unroll
  for (int j = 0; j < PTS; ++j) {
    int p = tid + BLOCK * j;
    pl[p] = pts[p];
    dist[j] = 1e10f;
  }
  __syncthreads();

  if (tid == 0) ids[0] = 0;
  float4 piv = pl[0];
  float cx = piv.x, cy = piv.y, cz = piv.z;

  for (int it = 1; it < SKP; ++it) {
    float best = -1.f; int besti = 0;
#pragma unroll
    for (int j = 0; j < PTS; ++j) {
      int p = tid + BLOCK * j;
      float4 f = pl[p];
      float d = sqdist(f.x, f.y, f.z, cx, cy, cz);
      d = fminf(dist[j], d);
      dist[j] = d;
      bool gt = d > best;
      best  = gt ? d : best;
      besti = gt ? p : besti;
    }
#pragma unroll
    for (int off = 32; off > 0; off >>= 1) {
      float ov = __shfl_xor(best, off);
      int   oi = __shfl_xor(besti, off);
      if (ov > best || (ov == best && oi < besti)) { best = ov; besti = oi; }
    }
    int par = it & 1;
    if (lane == 0) { s_v[par][wave] = best; s_i[par][wave] = besti; }
    __syncthreads();
    float v = -1.f; int i = 0x7fffffff;
    if (lane < NW) { v = s_v[par][lane]; i = s_i[par][lane]; }
#pragma unroll
    for (int off = NW >> 1; off > 0; off >>= 1) {
      float ov = __shfl_xor(v, off);
      int   oi = __shfl_xor(i, off);
      if (ov > v || (ov == v && oi < i)) { v = ov; i = oi; }
    }
    i = __shfl(i, 0);
    if (tid == 0) ids[it] = i;
    float4 pv = pl[i];
    cx = pv.x; cy = pv.y; cz = pv.z;
  }
}

// ---------------------------------------------------------------------------
// Skeletonization: wave per query, GRAM-form distances.
// Fast path: per-lane sorted top-KL (KL=8 for K=32), heads-merge K rounds
// -> t. Subset argument: t >= t_true always; rescan counts strict-less over
// ALL points, so ctot >= K detects t > t_true exactly -> rare fallback
// recomputes with full per-lane top-K. Tie-fill (exact lax.top_k semantics)
// runs on the verified t.
// ---------------------------------------------------------------------------
template<int K, int KL, int N, bool S3>
__global__ __launch_bounds__(256)
void sklnz_kernel(const float4* __restrict__ queries,
                  const void*   __restrict__ ptsv,
                  float4* __restrict__ outc,
                  float*  __restrict__ outr,
                  int M)
{
  const int CH = N / 64;
  int wave = threadIdx.x >> 6, lane = threadIdx.x & 63;
  int qid = blockIdx.x * 4 + wave;
  int b = qid / M;
  const float*  P3 = (const float*)ptsv + (size_t)b * N * 3;
  const float4* P4 = (const float4*)ptsv + (size_t)b * N;
  float4 q = queries[qid];
  float q2 = __fadd_rn(__fadd_rn(__fmul_rn(q.x, q.x), __fmul_rn(q.y, q.y)),
                       __fmul_rn(q.z, q.z));

  __shared__ float heads[4][64][K + 1];

  // ---- fast scan: per-lane sorted top-KL ----
  float a[KL];
#pragma unroll
  for (int s = 0; s < KL; ++s) a[s] = 3.0e38f;
  for (int j = 0; j < CH; ++j) {
    int p = lane + 64 * j;
    float px, py, pz;
    if (S3) { px = P3[3*p]; py = P3[3*p+1]; pz = P3[3*p+2]; }
    else    { float4 f = P4[p]; px = f.x; py = f.y; pz = f.z; }
    float d = d2gram(px, py, pz, q.x, q.y, q.z, q2);
#pragma unroll
    for (int s = KL - 1; s > 0; --s) a[s] = fminf(a[s], fmaxf(a[s-1], d));
    a[0] = fminf(a[0], d);
  }
  // ---- merge: K rounds over per-lane lists (sentinel-terminated) ----
#pragma unroll
  for (int s = 0; s < KL; ++s) heads[wave][lane][s] = a[s];
  heads[wave][lane][KL] = 3.1e38f;
  int h = 0; float t = 0.f;
  for (int r = 0; r < K; ++r) {
    float mv = heads[wave][lane][h];
    int   ml = lane;
#pragma unroll
    for (int off = 32; off > 0; off >>= 1) {
      float ov = __shfl_xor(mv, off);
      int   ol = __shfl_xor(ml, off);
      if (ov < mv || (ov == mv && ol < ml)) { mv = ov; ml = ol; }
    }
    t = mv;
    if (ml == lane) h++;
  }

  // ---- rescan: accumulate d < t, count, per-lane first d == t ----
  float sx = 0.f, sy = 0.f, sz = 0.f, sr = 0.f;
  int cl = 0;
  int myNext = 0x7fffffff;
  for (int j = 0; j < CH; ++j) {
    int p = lane + 64 * j;
    float px, py, pz;
    if (S3) { px = P3[3*p]; py = P3[3*p+1]; pz = P3[3*p+2]; }
    else    { float4 f = P4[p]; px = f.x; py = f.y; pz = f.z; }
    float d = d2gram(px, py, pz, q.x, q.y, q.z, q2);
    if (d < t) { sx += px; sy += py; sz += pz; sr += sqrtf(fmaxf(d, 0.f)); cl++; }
    else if (d == t && myNext == 0x7fffffff) myNext = p;
  }
  int ctot = cl;
#pragma unroll
  for (int off = 32; off > 0; off >>= 1) ctot += __shfl_xor(ctot, off);

  if constexpr (KL < K) {
    if (ctot >= K) {
      // ---- exact fallback: full per-lane top-K (rare) ----
      float a2[K];
#pragma unroll
      for (int s = 0; s < K; ++s) a2[s] = 3.0e38f;
      for (int j = 0; j < CH; ++j) {
        int p = lane + 64 * j;
        float px, py, pz;
        if (S3) { px = P3[3*p]; py = P3[3*p+1]; pz = P3[3*p+2]; }
        else    { float4 f = P4[p]; px = f.x; py = f.y; pz = f.z; }
        float d = d2gram(px, py, pz, q.x, q.y, q.z, q2);
#pragma unroll
        for (int s = K - 1; s > 0; --s) a2[s] = fminf(a2[s], fmaxf(a2[s-1], d));
        a2[0] = fminf(a2[0], d);
      }
#pragma unroll
      for (int s = 0; s < K; ++s) heads[wave][lane][s] = a2[s];
      heads[wave][lane][K] = 3.1e38f;
      h = 0;
      for (int r = 0; r < K; ++r) {
        float mv = heads[wave][lane][h];
        int   ml = lane;
#pragma unroll
        for (int off = 32; off > 0; off >>= 1) {
          float ov = __shfl_xor(mv, off);
          int   ol = __shfl_xor(ml, off);
          if (ov < mv || (ov == mv && ol < ml)) { mv = ov; ml = ol; }
        }
        t = mv;
        if (ml == lane) h++;
      }
      sx = sy = sz = sr = 0.f; cl = 0; myNext = 0x7fffffff;
      for (int j = 0; j < CH; ++j) {
        int p = lane + 64 * j;
        float px, py, pz;
        if (S3) { px = P3[3*p]; py = P3[3*p+1]; pz = P3[3*p+2]; }
        else    { float4 f = P4[p]; px = f.x; py = f.y; pz = f.z; }
        float d = d2gram(px, py, pz, q.x, q.y, q.z, q2);
        if (d < t) { sx += px; sy += py; sz += pz; sr += sqrtf(fmaxf(d, 0.f)); cl++; }
        else if (d == t && myNext == 0x7fffffff) myNext = p;
      }
      ctot = cl;
#pragma unroll
      for (int off = 32; off > 0; off >>= 1) ctot += __shfl_xor(ctot, off);
    }
  }

  int need = K - ctot;               // >= 1, <= multiplicity of t
  float rt = sqrtf(fmaxf(t, 0.f));

  for (int e = 0; e < need; ++e) {
    int mn = myNext;
#pragma unroll
    for (int off = 32; off > 0; off >>= 1) mn = min(mn, __shfl_xor(mn, off));
    if (myNext == mn) {              // unique owner (index sets disjoint mod 64)
      float px, py, pz;
      if (S3) { px = P3[3*mn]; py = P3[3*mn+1]; pz = P3[3*mn+2]; }
      else    { float4 f = P4[mn]; px = f.x; py = f.y; pz = f.z; }
      sx += px; sy += py; sz += pz; sr += rt;
      int nx = 0x7fffffff;
      for (int j = (mn - lane) / 64 + 1; j < CH; ++j) {
        int p = lane + 64 * j;
        float ux, uy, uz;
        if (S3) { ux = P3[3*p]; uy = P3[3*p+1]; uz = P3[3*p+2]; }
        else    { float4 f = P4[p]; ux = f.x; uy = f.y; uz = f.z; }
        float d = d2gram(ux, uy, uz, q.x, q.y, q.z, q2);
        if (d == t) { nx = p; break; }
      }
      myNext = nx;
    }
  }

#pragma unroll
  for (int off = 32; off > 0; off >>= 1) {
    sx += __shfl_xor(sx, off);
    sy += __shfl_xor(sy, off);
    sz += __shfl_xor(sz, off);
    sr += __shfl_xor(sr, off);
  }
  if (lane == 0) {
    const float inv = 1.0f / (float)K;
    outc[qid] = make_float4(sx * inv, sy * inv, sz * inv, 0.f);
    outr[qid] = sr * inv;
  }
}

// ---------------------------------------------------------------------------
__global__ void gather1_kernel(const float* __restrict__ xyz,
                               const int* __restrict__ ids,
                               float4* __restrict__ cen)
{
  int g = blockIdx.x * 256 + threadIdx.x;
  if (g >= BATCH * M1) return;
  int b = g / M1;
  size_t base = ((size_t)b * NPTS + ids[g]) * 3;
  cen[g] = make_float4(xyz[base], xyz[base+1], xyz[base+2], 0.f);
}

__global__ void gather2_kernel(const float4* __restrict__ cen4,
                               const float* __restrict__ rad1,
                               const int* __restrict__ ids2,
                               float4* __restrict__ cen2,
                               float* __restrict__ radg)
{
  int g = blockIdx.x * 256 + threadIdx.x;
  if (g >= BATCH * SKP) return;
  int b = g / SKP;
  int p = ids2[g];
  cen2[g] = cen4[(size_t)b * M1 + p];
  radg[g] = rad1[(size_t)b * M1 + p];
}

__global__ void finalize_kernel(const float4* __restrict__ cen,
                                const float* __restrict__ radg,
                                const float* __restrict__ rad2,
                                const float* __restrict__ tmpl,
                                float* __restrict__ out)
{
  int g = blockIdx.x * 256 + threadIdx.x;
  int s = g >> 7;
  int j = g & 127;
  float4 c = cen[s];
  float r = __fmul_rn(__fadd_rn(radg[s], rad2[s]), 1.5f);
  float tx = tmpl[3*j], ty = tmpl[3*j+1], tz = tmpl[3*j+2];
  float* sp = out + BATCH * SKP * 3;
  sp[3*g]     = __fadd_rn(c.x, __fmul_rn(r, tx));
  sp[3*g + 1] = __fadd_rn(c.y, __fmul_rn(r, ty));
  sp[3*g + 2] = __fadd_rn(c.z, __fmul_rn(r, tz));
  if (j == 0) {
    out[3*s] = c.x; out[3*s+1] = c.y; out[3*s+2] = c.z;
    out[BATCH*SKP*3 + BATCH*SKP*SPHN*3 + s] = r;
  }
}

// ---------------------------------------------------------------------------
extern "C" void kernel_launch(void* const* d_in, const int* in_sizes, int n_in,
                              void* d_out, int out_size, void* d_ws, size_t ws_size,
                              hipStream_t stream)
{
  const float* xyz  = (const float*)d_in[0];   // f32 [B, N, 3]
  const float* tmpl = (const float*)d_in[1];   // f32 [128, 3]
  float* out = (float*)d_out;                  // f32 outputs
  char* ws = (char*)d_ws;

  // total ws footprint: 422,912 B
  int*    ids1  = (int*)   (ws + 0);        //  32768 B
  float4* cen4a = (float4*)(ws + 32768);    // 131072 B
  float4* cen4b = (float4*)(ws + 163840);   // 131072 B
  float*  rad1  = (float*) (ws + 294912);   //  32768 B
  int*    ids2  = (int*)   (ws + 327680);   //   8192 B
  float4* cen2a = (float4*)(ws + 335872);   //  32768 B
  float4* cen2b = (float4*)(ws + 368640);   //  32768 B
  float*  radg  = (float*) (ws + 401408);   //   8192 B
  float*  rad2  = (float*) (ws + 409600);   //   8192 B
  unsigned long long* sync = (unsigned long long*)(ws + 417792); // 5120 B

  // Stage 1: batched-candidate exact FPS (4 blocks/batch)
  fps1_kernel<<<BATCH * 4, 1024, 0, stream>>>(xyz, ids1, sync);
  gather1_kernel<<<(BATCH * M1 + 255) / 256, 256, 0, stream>>>(xyz, ids1, cen4a);
  // two skeletonization passes, k=32 (fast per-lane top-8 + exact fallback)
  sklnz_kernel<KA, 8, NPTS, true><<<BATCH * M1 / 4, 256, 0, stream>>>(cen4a, xyz, cen4b, rad1, M1);
  sklnz_kernel<KA, 8, NPTS, true><<<BATCH * M1 / 4, 256, 0, stream>>>(cen4b, xyz, cen4a, rad1, M1);
  // Stage 2: FPS 2048 -> 512 on intermediate skeleton (cen4a)
  fps2_kernel<<<BATCH, 256, 0, stream>>>(cen4a, ids2);
  gather2_kernel<<<(BATCH * SKP + 255) / 256, 256, 0, stream>>>(cen4a, rad1, ids2, cen2a, radg);
  // two skeletonization passes, k=2 (KL == K -> exact, no fallback)
  sklnz_kernel<KB, KB, M1, false><<<BATCH * SKP / 4, 256, 0, stream>>>(cen2a, cen4a, cen2b, rad2, SKP);
  sklnz_kernel<KB, KB, M1, false><<<BATCH * SKP / 4, 256, 0, stream>>>(cen2b, cen4a, cen2a, rad2, SKP);
  // Outputs: centers, sphere points, radii (f32)
  finalize_kernel<<<BATCH * SKP * SPHN / 256, 256, 0, stream>>>(cen2a, radg, rad2, tmpl, out);
}

// Round 16
// 4079.322 us; speedup vs baseline: 5.5144x; 1.0818x over previous
//
#include <hip/hip_runtime.h>
#include <cstdint>

#define BATCH 4
#define NPTS  32768
#define QN    8192            /* points per fps1 block (4 blocks per batch) */
#define SKP   512
#define M1    (SKP*4)   /* 2048 */
#define KA    32
#define KB    2
#define SPHN  128

// FPS distance: reference _fps uses sum((x-c)**2) = ((dx*dx+dy*dy)+dz*dz),
// pinned round-to-nearest, NO fma contraction (bitwise == numpy).
__device__ __forceinline__ float sqdist(float px, float py, float pz,
                                        float cx, float cy, float cz) {
  float dx = px - cx, dy = py - cy, dz = pz - cz;
  return __fadd_rn(__fadd_rn(__fmul_rn(dx, dx), __fmul_rn(dy, dy)),
                   __fmul_rn(dz, dz));
}
// sklnz distance: reference _pairwise_sqdist uses c2 + p2 - 2*cp (Gram form).
__device__ __forceinline__ float d2gram(float px, float py, float pz,
                                        float qx, float qy, float qz, float q2) {
  float p2 = __fadd_rn(__fadd_rn(__fmul_rn(px, px), __fmul_rn(py, py)),
                       __fmul_rn(pz, pz));
  float cp = __fadd_rn(__fadd_rn(__fmul_rn(qx, px), __fmul_rn(qy, py)),
                       __fmul_rn(qz, pz));
  return __fsub_rn(__fadd_rn(q2, p2), __fadd_rn(cp, cp));
}

__device__ __forceinline__ unsigned long long shfl_xor_u64(unsigned long long v, int off) {
  int lo = __shfl_xor((int)(unsigned)v, off);
  int hi = __shfl_xor((int)(unsigned)(v >> 32), off);
  return ((unsigned long long)(unsigned)hi << 32) | (unsigned)lo;
}
__device__ __forceinline__ unsigned long long shfl_u64(unsigned long long v, int src) {
  int lo = __shfl((int)(unsigned)v, src);
  int hi = __shfl((int)(unsigned)(v >> 32), src);
  return ((unsigned long long)(unsigned)hi << 32) | (unsigned)lo;
}
__device__ __forceinline__ unsigned long long umax64(unsigned long long a, unsigned long long b) {
  return a > b ? a : b;
}
__device__ __forceinline__ unsigned long long umin64(unsigned long long a, unsigned long long b) {
  return a < b ? a : b;
}
// branch-free insert of v into descending sorted triple (k1>=k2>=k3)
__device__ __forceinline__ void ins3(unsigned long long& k1, unsigned long long& k2,
                                     unsigned long long& k3, unsigned long long v) {
  k3 = umax64(k3, umin64(k2, v));
  k2 = umax64(k2, umin64(k1, v));
  k1 = umax64(k1, v);
}

// ---------------------------------------------------------------------------
// Stage-1 FPS, batched-candidate exact algorithm, depth-2 candidates.
// 4 blocks/batch, xy in LDS, z[8]+dist[8] in VGPRs. Per super-round:
// multi-pivot scan, per-thread top-3 KEYS (key = distBits<<15 | 0x7FFF-idx:
// value desc, index asc == jnp.argmax order), wave top-3 merge, block
// publishes 32 keys (16 waves x top-2) + floor (max of wave-3rds) via
// relaxed agent-scope atomics (tag=rc, parity banks, poison 0xAAA=2730 >
// max rc 2047, cross-replay stale == fresh by determinism). All blocks
// redundantly pick from the 128-candidate union while unionMax > floorMax:
// every unpublished key <= floor and only decreases, so each pick is the
// exact global argmax; keys unique (index embedded) => first pick strict =>
// progress. Picked pivots (<=32) applied to dist[] next scan (idempotent
// chunks of 4). R15 measured J~2 with depth-1; depth-2 lowers the floor to
// wave-3rd and doubles the pool.
// ---------------------------------------------------------------------------
__global__ __launch_bounds__(1024)
void fps1_kernel(const float* __restrict__ xyz, int* __restrict__ ids,
                 unsigned long long* __restrict__ sync)
{
  int blk = blockIdx.x;
  int b = blk >> 2, sub = blk & 3;
  const float* X = xyz + (size_t)b * NPTS * 3;
  ids += (size_t)b * M1;
  int tid = threadIdx.x, lane = tid & 63, wave = tid >> 6;
  int base = sub * QN;

  __shared__ float2 xysh[QN];               // 65536 B
  __shared__ unsigned long long s_w[16][3]; // per-wave top-3 keys
  __shared__ float s_pivc[32][3];
  __shared__ int s_J;

  float zr[8], dist[8];
#pragma unroll
  for (int j = 0; j < 8; ++j) {
    int pl = tid + 1024 * j;
    int pg = base + pl;
    xysh[pl] = make_float2(X[3*pg], X[3*pg+1]);
    zr[j] = X[3*pg+2];
    dist[j] = 1e10f;
  }
  if (tid == 0) {
    s_pivc[0][0] = X[0]; s_pivc[0][1] = X[1]; s_pivc[0][2] = X[2];
    if (sub == 0) ids[0] = 0;
  }
  __syncthreads();

  int it = 1, J = 1, rc = 1;

  while (it < M1) {
    // ---- scan: apply J pivots in idempotent-padded chunks of 4 ----
    for (int jp0 = 0; jp0 < J; jp0 += 4) {
      float pxa[4], pya[4], pza[4];
#pragma unroll
      for (int l = 0; l < 4; ++l) {
        int jj = jp0 + l; jj = (jj < J) ? jj : jp0;   // re-apply is harmless (min)
        pxa[l] = s_pivc[jj][0]; pya[l] = s_pivc[jj][1]; pza[l] = s_pivc[jj][2];
      }
#pragma unroll
      for (int j = 0; j < 8; ++j) {
        int pl = tid + 1024 * j;
        float2 c2 = xysh[pl];
        float dd = dist[j];
#pragma unroll
        for (int l = 0; l < 4; ++l)
          dd = fminf(dd, sqdist(c2.x, c2.y, zr[j], pxa[l], pya[l], pza[l]));
        dist[j] = dd;
      }
    }
    // ---- per-thread top-3 keys ----
    unsigned long long k1 = 0, k2 = 0, k3 = 0;
#pragma unroll
    for (int j = 0; j < 8; ++j) {
      int pg = base + tid + 1024 * j;
      unsigned long long key =
          ((unsigned long long)__float_as_uint(dist[j]) << 15) |
          (unsigned)(0x7FFF - pg);
      ins3(k1, k2, k3, key);
    }
    // ---- wave top-3 merge ----
#pragma unroll
    for (int off = 32; off > 0; off >>= 1) {
      unsigned long long o1 = shfl_xor_u64(k1, off);
      unsigned long long o2 = shfl_xor_u64(k2, off);
      unsigned long long o3 = shfl_xor_u64(k3, off);
      ins3(k1, k2, k3, o1);
      ins3(k1, k2, k3, o2);
      ins3(k1, k2, k3, o3);
    }
    if (lane == 0) { s_w[wave][0] = k1; s_w[wave][1] = k2; s_w[wave][2] = k3; }
    __syncthreads();                       // barrier A
    if (wave == 0) {
      // block floor = max of wave-3rds
      unsigned long long fb = (lane < 16) ? s_w[lane][2] : 0;
#pragma unroll
      for (int off = 8; off > 0; off >>= 1) {
        unsigned long long o = shfl_xor_u64(fb, off);
        if (o > fb) fb = o;
      }
      fb = shfl_u64(fb, 0);
      unsigned tag = (unsigned)rc;
      int par = rc & 1;
      int sbase = ((b * 2 + par) * 4 + sub) * 40;
      unsigned long long mycand = 0;
      if (lane < 16)      mycand = s_w[lane][0];
      else if (lane < 32) mycand = s_w[lane - 16][1];
      if (lane < 32)
        __hip_atomic_store(&sync[sbase + lane], (mycand << 12) | tag,
                           __ATOMIC_RELAXED, __HIP_MEMORY_SCOPE_AGENT);
      if (lane == 32)
        __hip_atomic_store(&sync[sbase + 32], (fb << 12) | tag,
                           __ATOMIC_RELAXED, __HIP_MEMORY_SCOPE_AGENT);
      // poll: each lane 2 candidate slots (128 total) + lanes 0-3 floors
      int rel = (sub + (lane >> 4)) & 3;
      int cb = ((b * 2 + par) * 4 + rel) * 40;
      int c0s = cb + (lane & 15);
      int c1s = cb + 16 + (lane & 15);
      int fsl = ((b * 2 + par) * 4 + ((sub + lane) & 3)) * 40 + 32;
      unsigned long long ck0 = 0, ck1 = 0, flr = 0;
      bool n0 = true, n1 = true, nf = (lane < 4);
      while (__any(n0 || n1 || nf)) {
        if (n0) {
          unsigned long long v = __hip_atomic_load(&sync[c0s],
                                  __ATOMIC_RELAXED, __HIP_MEMORY_SCOPE_AGENT);
          if ((unsigned)(v & 0xFFFu) == tag) { ck0 = v >> 12; n0 = false; }
        }
        if (n1) {
          unsigned long long v = __hip_atomic_load(&sync[c1s],
                                  __ATOMIC_RELAXED, __HIP_MEMORY_SCOPE_AGENT);
          if ((unsigned)(v & 0xFFFu) == tag) { ck1 = v >> 12; n1 = false; }
        }
        if (nf) {
          unsigned long long v = __hip_atomic_load(&sync[fsl],
                                  __ATOMIC_RELAXED, __HIP_MEMORY_SCOPE_AGENT);
          if ((unsigned)(v & 0xFFFu) == tag) { flr = v >> 12; nf = false; }
        }
      }
      unsigned long long f = umax64(umax64(shfl_u64(flr, 0), shfl_u64(flr, 1)),
                                    umax64(shfl_u64(flr, 2), shfl_u64(flr, 3)));
      // candidate coords (2 per lane)
      int ci0 = 0x7FFF - (int)(ck0 & 0x7FFFu);
      int ci1 = 0x7FFF - (int)(ck1 & 0x7FFFu);
      float cx0 = X[3*ci0], cy0 = X[3*ci0+1], cz0 = X[3*ci0+2];
      float cx1 = X[3*ci1], cy1 = X[3*ci1+1], cz1 = X[3*ci1+2];
      int Jn = 0;
      while (it + Jn < M1 && Jn < 32) {
        unsigned long long mk = umax64(ck0, ck1);
#pragma unroll
        for (int off = 32; off > 0; off >>= 1) {
          unsigned long long o = shfl_xor_u64(mk, off);
          if (o > mk) mk = o;
        }
        if (!(mk > f)) break;              // outside point could exceed -> exchange
        unsigned long long b0 = __ballot(ck0 == mk);
        float px, py, pz;
        if (b0) {
          int wl = __ffsll((long long)b0) - 1;
          px = __shfl(cx0, wl); py = __shfl(cy0, wl); pz = __shfl(cz0, wl);
        } else {
          unsigned long long b1 = __ballot(ck1 == mk);
          int wl = __ffsll((long long)b1) - 1;
          px = __shfl(cx1, wl); py = __shfl(cy1, wl); pz = __shfl(cz1, wl);
        }
        if (lane == 0) {
          s_pivc[Jn][0] = px; s_pivc[Jn][1] = py; s_pivc[Jn][2] = pz;
          if (sub == 0) ids[it + Jn] = 0x7FFF - (int)(mk & 0x7FFFu);
        }
        float d0 = sqdist(cx0, cy0, cz0, px, py, pz);
        float n0v = fminf(__uint_as_float((unsigned)(ck0 >> 15)), d0);
        ck0 = ((unsigned long long)__float_as_uint(n0v) << 15) | (ck0 & 0x7FFFu);
        float d1 = sqdist(cx1, cy1, cz1, px, py, pz);
        float n1v = fminf(__uint_as_float((unsigned)(ck1 >> 15)), d1);
        ck1 = ((unsigned long long)__float_as_uint(n1v) << 15) | (ck1 & 0x7FFFu);
        ++Jn;
      }
      if (lane == 0) s_J = Jn;
    }
    __syncthreads();                       // barrier B
    J = s_J;
    it += J;
    rc += 1;
  }
}

// ---------------------------------------------------------------------------
// Stage-2 FPS, batched picks intra-block (no atomics): 1024 threads,
// 2 pts/thread in registers, pl[] in LDS for candidate coord lookup.
// Same key/floor machinery as fps1: per-thread top-3, wave top-3 merge,
// 32 candidates (16 waves x top-2), floor = max wave-3rd; picks exact.
// ---------------------------------------------------------------------------
__global__ __launch_bounds__(1024)
void fps2_kernel(const float4* __restrict__ pts, int* __restrict__ ids)
{
  int b = blockIdx.x;
  pts += (size_t)b * M1;
  ids += (size_t)b * SKP;
  int tid = threadIdx.x, lane = tid & 63, wave = tid >> 6;

  __shared__ float4 pl[M1];                 // 32768 B
  __shared__ unsigned long long s_w[16][3];
  __shared__ float s_pivc[16][3];
  __shared__ int s_J;

  float4 f0 = pts[tid], f1 = pts[tid + 1024];
  pl[tid] = f0; pl[tid + 1024] = f1;
  float dist0 = 1e10f, dist1 = 1e10f;
  if (tid == 0) {
    ids[0] = 0;
    s_pivc[0][0] = f0.x; s_pivc[0][1] = f0.y; s_pivc[0][2] = f0.z;
  }
  __syncthreads();

  int it = 1, J = 1;

  while (it < SKP) {
    for (int jp0 = 0; jp0 < J; jp0 += 4) {
      float pxa[4], pya[4], pza[4];
#pragma unroll
      for (int l = 0; l < 4; ++l) {
        int jj = jp0 + l; jj = (jj < J) ? jj : jp0;
        pxa[l] = s_pivc[jj][0]; pya[l] = s_pivc[jj][1]; pza[l] = s_pivc[jj][2];
      }
#pragma unroll
      for (int l = 0; l < 4; ++l) {
        dist0 = fminf(dist0, sqdist(f0.x, f0.y, f0.z, pxa[l], pya[l], pza[l]));
        dist1 = fminf(dist1, sqdist(f1.x, f1.y, f1.z, pxa[l], pya[l], pza[l]));
      }
    }
    unsigned long long k1, k2 = 0, k3 = 0;
    k1 = ((unsigned long long)__float_as_uint(dist0) << 15) | (unsigned)(0x7FFF - tid);
    {
      unsigned long long key =
          ((unsigned long long)__float_as_uint(dist1) << 15) | (unsigned)(0x7FFF - (tid + 1024));
      ins3(k1, k2, k3, key);
    }
#pragma unroll
    for (int off = 32; off > 0; off >>= 1) {
      unsigned long long o1 = shfl_xor_u64(k1, off);
      unsigned long long o2 = shfl_xor_u64(k2, off);
      unsigned long long o3 = shfl_xor_u64(k3, off);
      ins3(k1, k2, k3, o1);
      ins3(k1, k2, k3, o2);
      ins3(k1, k2, k3, o3);
    }
    if (lane == 0) { s_w[wave][0] = k1; s_w[wave][1] = k2; s_w[wave][2] = k3; }
    __syncthreads();                       // barrier A
    if (wave == 0) {
      unsigned long long fb = (lane < 16) ? s_w[lane][2] : 0;
#pragma unroll
      for (int off = 8; off > 0; off >>= 1) {
        unsigned long long o = shfl_xor_u64(fb, off);
        if (o > fb) fb = o;
      }
      unsigned long long f = shfl_u64(fb, 0);
      unsigned long long ck = 0;
      if (lane < 16)      ck = s_w[lane][0];
      else if (lane < 32) ck = s_w[lane - 16][1];
      int ci = (0x7FFF - (int)(ck & 0x7FFFu)) & (M1 - 1);
      float4 c = pl[ci];
      int Jn = 0;
      while (it + Jn < SKP && Jn < 16) {
        unsigned long long mk = ck;
#pragma unroll
        for (int off = 32; off > 0; off >>= 1) {
          unsigned long long o = shfl_xor_u64(mk, off);
          if (o > mk) mk = o;
        }
        if (!(mk > f)) break;
        unsigned long long ball = __ballot(ck == mk);
        int wl = __ffsll((long long)ball) - 1;
        float px = __shfl(c.x, wl), py = __shfl(c.y, wl), pz = __shfl(c.z, wl);
        if (lane == 0) {
          s_pivc[Jn][0] = px; s_pivc[Jn][1] = py; s_pivc[Jn][2] = pz;
          ids[it + Jn] = 0x7FFF - (int)(mk & 0x7FFFu);
        }
        float d = sqdist(c.x, c.y, c.z, px, py, pz);
        float nv = fminf(__uint_as_float((unsigned)(ck >> 15)), d);
        ck = ((unsigned long long)__float_as_uint(nv) << 15) | (ck & 0x7FFFu);
        ++Jn;
      }
      if (lane == 0) s_J = Jn;
    }
    __syncthreads();                       // barrier B
    J = s_J;
    it += J;
  }
}

// ---------------------------------------------------------------------------
// Skeletonization: wave per query, GRAM-form distances.
// Fast path: per-lane sorted top-KL (KL=8 for K=32), heads-merge K rounds
// -> t. Subset argument: t >= t_true always; rescan counts strict-less over
// ALL points, so ctot >= K detects t > t_true exactly -> rare fallback
// recomputes with full per-lane top-K. Tie-fill (exact lax.top_k semantics)
// runs on the verified t.
// ---------------------------------------------------------------------------
template<int K, int KL, int N, bool S3>
__global__ __launch_bounds__(256)
void sklnz_kernel(const float4* __restrict__ queries,
                  const void*   __restrict__ ptsv,
                  float4* __restrict__ outc,
                  float*  __restrict__ outr,
                  int M)
{
  const int CH = N / 64;
  int wave = threadIdx.x >> 6, lane = threadIdx.x & 63;
  int qid = blockIdx.x * 4 + wave;
  int b = qid / M;
  const float*  P3 = (const float*)ptsv + (size_t)b * N * 3;
  const float4* P4 = (const float4*)ptsv + (size_t)b * N;
  float4 q = queries[qid];
  float q2 = __fadd_rn(__fadd_rn(__fmul_rn(q.x, q.x), __fmul_rn(q.y, q.y)),
                       __fmul_rn(q.z, q.z));

  __shared__ float heads[4][64][K + 1];

  // ---- fast scan: per-lane sorted top-KL ----
  float a[KL];
#pragma unroll
  for (int s = 0; s < KL; ++s) a[s] = 3.0e38f;
  for (int j = 0; j < CH; ++j) {
    int p = lane + 64 * j;
    float px, py, pz;
    if (S3) { px = P3[3*p]; py = P3[3*p+1]; pz = P3[3*p+2]; }
    else    { float4 f = P4[p]; px = f.x; py = f.y; pz = f.z; }
    float d = d2gram(px, py, pz, q.x, q.y, q.z, q2);
#pragma unroll
    for (int s = KL - 1; s > 0; --s) a[s] = fminf(a[s], fmaxf(a[s-1], d));
    a[0] = fminf(a[0], d);
  }
  // ---- merge: K rounds over per-lane lists (sentinel-terminated) ----
#pragma unroll
  for (int s = 0; s < KL; ++s) heads[wave][lane][s] = a[s];
  heads[wave][lane][KL] = 3.1e38f;
  int h = 0; float t = 0.f;
  for (int r = 0; r < K; ++r) {
    float mv = heads[wave][lane][h];
    int   ml = lane;
#pragma unroll
    for (int off = 32; off > 0; off >>= 1) {
      float ov = __shfl_xor(mv, off);
      int   ol = __shfl_xor(ml, off);
      if (ov < mv || (ov == mv && ol < ml)) { mv = ov; ml = ol; }
    }
    t = mv;
    if (ml == lane) h++;
  }

  // ---- rescan: accumulate d < t, count, per-lane first d == t ----
  float sx = 0.f, sy = 0.f, sz = 0.f, sr = 0.f;
  int cl = 0;
  int myNext = 0x7fffffff;
  for (int j = 0; j < CH; ++j) {
    int p = lane + 64 * j;
    float px, py, pz;
    if (S3) { px = P3[3*p]; py = P3[3*p+1]; pz = P3[3*p+2]; }
    else    { float4 f = P4[p]; px = f.x; py = f.y; pz = f.z; }
    float d = d2gram(px, py, pz, q.x, q.y, q.z, q2);
    if (d < t) { sx += px; sy += py; sz += pz; sr += sqrtf(fmaxf(d, 0.f)); cl++; }
    else if (d == t && myNext == 0x7fffffff) myNext = p;
  }
  int ctot = cl;
#pragma unroll
  for (int off = 32; off > 0; off >>= 1) ctot += __shfl_xor(ctot, off);

  if constexpr (KL < K) {
    if (ctot >= K) {
      // ---- exact fallback: full per-lane top-K (rare) ----
      float a2[K];
#pragma unroll
      for (int s = 0; s < K; ++s) a2[s] = 3.0e38f;
      for (int j = 0; j < CH; ++j) {
        int p = lane + 64 * j;
        float px, py, pz;
        if (S3) { px = P3[3*p]; py = P3[3*p+1]; pz = P3[3*p+2]; }
        else    { float4 f = P4[p]; px = f.x; py = f.y; pz = f.z; }
        float d = d2gram(px, py, pz, q.x, q.y, q.z, q2);
#pragma unroll
        for (int s = K - 1; s > 0; --s) a2[s] = fminf(a2[s], fmaxf(a2[s-1], d));
        a2[0] = fminf(a2[0], d);
      }
#pragma unroll
      for (int s = 0; s < K; ++s) heads[wave][lane][s] = a2[s];
      heads[wave][lane][K] = 3.1e38f;
      h = 0;
      for (int r = 0; r < K; ++r) {
        float mv = heads[wave][lane][h];
        int   ml = lane;
#pragma unroll
        for (int off = 32; off > 0; off >>= 1) {
          float ov = __shfl_xor(mv, off);
          int   ol = __shfl_xor(ml, off);
          if (ov < mv || (ov == mv && ol < ml)) { mv = ov; ml = ol; }
        }
        t = mv;
        if (ml == lane) h++;
      }
      sx = sy = sz = sr = 0.f; cl = 0; myNext = 0x7fffffff;
      for (int j = 0; j < CH; ++j) {
        int p = lane + 64 * j;
        float px, py, pz;
        if (S3) { px = P3[3*p]; py = P3[3*p+1]; pz = P3[3*p+2]; }
        else    { float4 f = P4[p]; px = f.x; py = f.y; pz = f.z; }
        float d = d2gram(px, py, pz, q.x, q.y, q.z, q2);
        if (d < t) { sx += px; sy += py; sz += pz; sr += sqrtf(fmaxf(d, 0.f)); cl++; }
        else if (d == t && myNext == 0x7fffffff) myNext = p;
      }
      ctot = cl;
#pragma unroll
      for (int off = 32; off > 0; off >>= 1) ctot += __shfl_xor(ctot, off);
    }
  }

  int need = K - ctot;               // >= 1, <= multiplicity of t
  float rt = sqrtf(fmaxf(t, 0.f));

  for (int e = 0; e < need; ++e) {
    int mn = myNext;
#pragma unroll
    for (int off = 32; off > 0; off >>= 1) mn = min(mn, __shfl_xor(mn, off));
    if (myNext == mn) {              // unique owner (index sets disjoint mod 64)
      float px, py, pz;
      if (S3) { px = P3[3*mn]; py = P3[3*mn+1]; pz = P3[3*mn+2]; }
      else    { float4 f = P4[mn]; px = f.x; py = f.y; pz = f.z; }
      sx += px; sy += py; sz += pz; sr += rt;
      int nx = 0x7fffffff;
      for (int j = (mn - lane) / 64 + 1; j < CH; ++j) {
        int p = lane + 64 * j;
        float ux, uy, uz;
        if (S3) { ux = P3[3*p]; uy = P3[3*p+1]; uz = P3[3*p+2]; }
        else    { float4 f = P4[p]; ux = f.x; uy = f.y; uz = f.z; }
        float d = d2gram(ux, uy, uz, q.x, q.y, q.z, q2);
        if (d == t) { nx = p; break; }
      }
      myNext = nx;
    }
  }

#pragma unroll
  for (int off = 32; off > 0; off >>= 1) {
    sx += __shfl_xor(sx, off);
    sy += __shfl_xor(sy, off);
    sz += __shfl_xor(sz, off);
    sr += __shfl_xor(sr, off);
  }
  if (lane == 0) {
    const float inv = 1.0f / (float)K;
    outc[qid] = make_float4(sx * inv, sy * inv, sz * inv, 0.f);
    outr[qid] = sr * inv;
  }
}

// ---------------------------------------------------------------------------
__global__ void gather1_kernel(const float* __restrict__ xyz,
                               const int* __restrict__ ids,
                               float4* __restrict__ cen)
{
  int g = blockIdx.x * 256 + threadIdx.x;
  if (g >= BATCH * M1) return;
  int b = g / M1;
  size_t base = ((size_t)b * NPTS + ids[g]) * 3;
  cen[g] = make_float4(xyz[base], xyz[base+1], xyz[base+2], 0.f);
}

__global__ void gather2_kernel(const float4* __restrict__ cen4,
                               const float* __restrict__ rad1,
                               const int* __restrict__ ids2,
                               float4* __restrict__ cen2,
                               float* __restrict__ radg)
{
  int g = blockIdx.x * 256 + threadIdx.x;
  if (g >= BATCH * SKP) return;
  int b = g / SKP;
  int p = ids2[g];
  cen2[g] = cen4[(size_t)b * M1 + p];
  radg[g] = rad1[(size_t)b * M1 + p];
}

__global__ void finalize_kernel(const float4* __restrict__ cen,
                                const float* __restrict__ radg,
                                const float* __restrict__ rad2,
                                const float* __restrict__ tmpl,
                                float* __restrict__ out)
{
  int g = blockIdx.x * 256 + threadIdx.x;
  int s = g >> 7;
  int j = g & 127;
  float4 c = cen[s];
  float r = __fmul_rn(__fadd_rn(radg[s], rad2[s]), 1.5f);
  float tx = tmpl[3*j], ty = tmpl[3*j+1], tz = tmpl[3*j+2];
  float* sp = out + BATCH * SKP * 3;
  sp[3*g]     = __fadd_rn(c.x, __fmul_rn(r, tx));
  sp[3*g + 1] = __fadd_rn(c.y, __fmul_rn(r, ty));
  sp[3*g + 2] = __fadd_rn(c.z, __fmul_rn(r, tz));
  if (j == 0) {
    out[3*s] = c.x; out[3*s+1] = c.y; out[3*s+2] = c.z;
    out[BATCH*SKP*3 + BATCH*SKP*SPHN*3 + s] = r;
  }
}

// ---------------------------------------------------------------------------
extern "C" void kernel_launch(void* const* d_in, const int* in_sizes, int n_in,
                              void* d_out, int out_size, void* d_ws, size_t ws_size,
                              hipStream_t stream)
{
  const float* xyz  = (const float*)d_in[0];   // f32 [B, N, 3]
  const float* tmpl = (const float*)d_in[1];   // f32 [128, 3]
  float* out = (float*)d_out;                  // f32 outputs
  char* ws = (char*)d_ws;

  // total ws footprint: 428,032 B
  int*    ids1  = (int*)   (ws + 0);        //  32768 B
  float4* cen4a = (float4*)(ws + 32768);    // 131072 B
  float4* cen4b = (float4*)(ws + 163840);   // 131072 B
  float*  rad1  = (float*) (ws + 294912);   //  32768 B
  int*    ids2  = (int*)   (ws + 327680);   //   8192 B
  float4* cen2a = (float4*)(ws + 335872);   //  32768 B
  float4* cen2b = (float4*)(ws + 368640);   //  32768 B
  float*  radg  = (float*) (ws + 401408);   //   8192 B
  float*  rad2  = (float*) (ws + 409600);   //   8192 B
  unsigned long long* sync = (unsigned long long*)(ws + 417792); // 10240 B

  // Stage 1: batched-candidate exact FPS (4 blocks/batch, depth-2)
  fps1_kernel<<<BATCH * 4, 1024, 0, stream>>>(xyz, ids1, sync);
  gather1_kernel<<<(BATCH * M1 + 255) / 256, 256, 0, stream>>>(xyz, ids1, cen4a);
  // two skeletonization passes, k=32 (fast per-lane top-8 + exact fallback)
  sklnz_kernel<KA, 8, NPTS, true><<<BATCH * M1 / 4, 256, 0, stream>>>(cen4a, xyz, cen4b, rad1, M1);
  sklnz_kernel<KA, 8, NPTS, true><<<BATCH * M1 / 4, 256, 0, stream>>>(cen4b, xyz, cen4a, rad1, M1);
  // Stage 2: batched-pick FPS 2048 -> 512 (1 block/batch, intra-block)
  fps2_kernel<<<BATCH, 1024, 0, stream>>>(cen4a, ids2);
  gather2_kernel<<<(BATCH * SKP + 255) / 256, 256, 0, stream>>>(cen4a, rad1, ids2, cen2a, radg);
  // two skeletonization passes, k=2 (KL == K -> exact, no fallback)
  sklnz_kernel<KB, KB, M1, false><<<BATCH * SKP / 4, 256, 0, stream>>>(cen2a, cen4a, cen2b, rad2, SKP);
  sklnz_kernel<KB, KB, M1, false><<<BATCH * SKP / 4, 256, 0, stream>>>(cen2b, cen4a, cen2a, rad2, SKP);
  // Outputs: centers, sphere points, radii (f32)
  finalize_kernel<<<BATCH * SKP * SPHN / 256, 256, 0, stream>>>(cen2a, radg, rad2, tmpl, out);
}

// Round 17
// 4028.873 us; speedup vs baseline: 5.5835x; 1.0125x over previous
//
#include <hip/hip_runtime.h>
#include <cstdint>

#define BATCH 4
#define NPTS  32768
#define QN    8192            /* points per fps1 block (4 blocks per batch) */
#define SKP   512
#define M1    (SKP*4)   /* 2048 */
#define KA    32
#define KB    2
#define SPHN  128

// FPS distance: reference _fps uses sum((x-c)**2) = ((dx*dx+dy*dy)+dz*dz),
// pinned round-to-nearest, NO fma contraction (bitwise == numpy).
__device__ __forceinline__ float sqdist(float px, float py, float pz,
                                        float cx, float cy, float cz) {
  float dx = px - cx, dy = py - cy, dz = pz - cz;
  return __fadd_rn(__fadd_rn(__fmul_rn(dx, dx), __fmul_rn(dy, dy)),
                   __fmul_rn(dz, dz));
}
// sklnz distance: reference _pairwise_sqdist uses c2 + p2 - 2*cp (Gram form).
__device__ __forceinline__ float d2gram(float px, float py, float pz,
                                        float qx, float qy, float qz, float q2) {
  float p2 = __fadd_rn(__fadd_rn(__fmul_rn(px, px), __fmul_rn(py, py)),
                       __fmul_rn(pz, pz));
  float cp = __fadd_rn(__fadd_rn(__fmul_rn(qx, px), __fmul_rn(qy, py)),
                       __fmul_rn(qz, pz));
  return __fsub_rn(__fadd_rn(q2, p2), __fadd_rn(cp, cp));
}

__device__ __forceinline__ unsigned long long shfl_xor_u64(unsigned long long v, int off) {
  int lo = __shfl_xor((int)(unsigned)v, off);
  int hi = __shfl_xor((int)(unsigned)(v >> 32), off);
  return ((unsigned long long)(unsigned)hi << 32) | (unsigned)lo;
}
__device__ __forceinline__ unsigned long long shfl_u64(unsigned long long v, int src) {
  int lo = __shfl((int)(unsigned)v, src);
  int hi = __shfl((int)(unsigned)(v >> 32), src);
  return ((unsigned long long)(unsigned)hi << 32) | (unsigned)lo;
}
__device__ __forceinline__ unsigned long long umax64(unsigned long long a, unsigned long long b) {
  return a > b ? a : b;
}
__device__ __forceinline__ unsigned long long umin64(unsigned long long a, unsigned long long b) {
  return a < b ? a : b;
}
// branch-free insert into descending sorted triple / quad
__device__ __forceinline__ void ins3(unsigned long long& k1, unsigned long long& k2,
                                     unsigned long long& k3, unsigned long long v) {
  k3 = umax64(k3, umin64(k2, v));
  k2 = umax64(k2, umin64(k1, v));
  k1 = umax64(k1, v);
}
__device__ __forceinline__ void ins4(unsigned long long& k1, unsigned long long& k2,
                                     unsigned long long& k3, unsigned long long& k4,
                                     unsigned long long v) {
  k4 = umax64(k4, umin64(k3, v));
  k3 = umax64(k3, umin64(k2, v));
  k2 = umax64(k2, umin64(k1, v));
  k1 = umax64(k1, v);
}

// ---------------------------------------------------------------------------
// Stage-1 FPS, batched-candidate exact algorithm, depth-3 candidates.
// 4 blocks/batch, xy in LDS, z[8]+dist[8] in VGPRs. Per super-round:
// multi-pivot scan, per-thread top-4 KEYS (key = distBits<<15 | 0x7FFF-idx:
// value desc, index asc == jnp.argmax order), wave top-4 merge, block
// publishes 48 keys (16 waves x top-3) + floor (max of wave-4ths) via
// relaxed agent-scope atomics (tag=rc, parity banks, poison 0xAAA=2730 >
// max rc 2047, cross-replay stale == fresh by determinism). All blocks
// redundantly pick from the 192-candidate union while unionMax > floorMax:
// unpublished keys <= floor (if a thread's 4th exceeded the floor, 4 merged
// keys would exceed the 4th-largest merged value -- contradiction) and only
// decrease, so each pick is the exact global argmax; keys unique => first
// pick strict => progress. Picked pivots (<=48) applied next scan.
// Picks write cen4a directly (gather1 kernel eliminated).
// ---------------------------------------------------------------------------
__global__ __launch_bounds__(1024)
void fps1_kernel(const float* __restrict__ xyz, float4* __restrict__ cen4a,
                 unsigned long long* __restrict__ sync)
{
  int blk = blockIdx.x;
  int b = blk >> 2, sub = blk & 3;
  const float* X = xyz + (size_t)b * NPTS * 3;
  cen4a += (size_t)b * M1;
  int tid = threadIdx.x, lane = tid & 63, wave = tid >> 6;
  int base = sub * QN;

  __shared__ float2 xysh[QN];               // 65536 B
  __shared__ unsigned long long s_w[16][4]; // per-wave top-4 keys
  __shared__ float s_pivc[48][3];
  __shared__ int s_J;

  float zr[8], dist[8];
#pragma unroll
  for (int j = 0; j < 8; ++j) {
    int pl = tid + 1024 * j;
    int pg = base + pl;
    xysh[pl] = make_float2(X[3*pg], X[3*pg+1]);
    zr[j] = X[3*pg+2];
    dist[j] = 1e10f;
  }
  if (tid == 0) {
    s_pivc[0][0] = X[0]; s_pivc[0][1] = X[1]; s_pivc[0][2] = X[2];
    if (sub == 0) cen4a[0] = make_float4(X[0], X[1], X[2], 0.f);
  }
  __syncthreads();

  int it = 1, J = 1, rc = 1;

  while (it < M1) {
    // ---- scan: apply J pivots in idempotent-padded chunks of 4 ----
    for (int jp0 = 0; jp0 < J; jp0 += 4) {
      float pxa[4], pya[4], pza[4];
#pragma unroll
      for (int l = 0; l < 4; ++l) {
        int jj = jp0 + l; jj = (jj < J) ? jj : jp0;   // re-apply is harmless (min)
        pxa[l] = s_pivc[jj][0]; pya[l] = s_pivc[jj][1]; pza[l] = s_pivc[jj][2];
      }
#pragma unroll
      for (int j = 0; j < 8; ++j) {
        int pl = tid + 1024 * j;
        float2 c2 = xysh[pl];
        float dd = dist[j];
#pragma unroll
        for (int l = 0; l < 4; ++l)
          dd = fminf(dd, sqdist(c2.x, c2.y, zr[j], pxa[l], pya[l], pza[l]));
        dist[j] = dd;
      }
    }
    // ---- per-thread top-4 keys ----
    unsigned long long k1 = 0, k2 = 0, k3 = 0, k4 = 0;
#pragma unroll
    for (int j = 0; j < 8; ++j) {
      int pg = base + tid + 1024 * j;
      unsigned long long key =
          ((unsigned long long)__float_as_uint(dist[j]) << 15) |
          (unsigned)(0x7FFF - pg);
      ins4(k1, k2, k3, k4, key);
    }
    // ---- wave top-4 merge ----
#pragma unroll
    for (int off = 32; off > 0; off >>= 1) {
      unsigned long long o1 = shfl_xor_u64(k1, off);
      unsigned long long o2 = shfl_xor_u64(k2, off);
      unsigned long long o3 = shfl_xor_u64(k3, off);
      unsigned long long o4 = shfl_xor_u64(k4, off);
      ins4(k1, k2, k3, k4, o1);
      ins4(k1, k2, k3, k4, o2);
      ins4(k1, k2, k3, k4, o3);
      ins4(k1, k2, k3, k4, o4);
    }
    if (lane == 0) {
      s_w[wave][0] = k1; s_w[wave][1] = k2; s_w[wave][2] = k3; s_w[wave][3] = k4;
    }
    __syncthreads();                       // barrier A
    if (wave == 0) {
      // block floor = max of wave-4ths
      unsigned long long fb = (lane < 16) ? s_w[lane][3] : 0;
#pragma unroll
      for (int off = 8; off > 0; off >>= 1) {
        unsigned long long o = shfl_xor_u64(fb, off);
        if (o > fb) fb = o;
      }
      fb = shfl_u64(fb, 0);
      unsigned tag = (unsigned)rc;
      int par = rc & 1;
      int sbase = ((b * 2 + par) * 4 + sub) * 56;
      if (lane < 48)
        __hip_atomic_store(&sync[sbase + lane],
                           (s_w[lane & 15][lane >> 4] << 12) | tag,
                           __ATOMIC_RELAXED, __HIP_MEMORY_SCOPE_AGENT);
      if (lane == 48)
        __hip_atomic_store(&sync[sbase + 48], (fb << 12) | tag,
                           __ATOMIC_RELAXED, __HIP_MEMORY_SCOPE_AGENT);
      // ---- gather the 192-candidate union: lane handles q = lane + 64k ----
      unsigned long long ck[3];
      int slots[3]; bool need[3];
#pragma unroll
      for (int k = 0; k < 3; ++k) {
        int q = lane + 64 * k;
        int r = q / 48, s = q % 48;
        if (r == 0) { ck[k] = s_w[s & 15][s >> 4]; need[k] = false; slots[k] = 0; }
        else {
          slots[k] = ((b * 2 + par) * 4 + ((sub + r) & 3)) * 56 + s;
          need[k] = true; ck[k] = 0;
        }
      }
      bool needf = (lane < 3);
      int fslot = ((b * 2 + par) * 4 + ((sub + 1 + lane) & 3)) * 56 + 48;
      unsigned long long flr = 0;
      while (__any(need[0] || need[1] || need[2] || needf)) {
#pragma unroll
        for (int k = 0; k < 3; ++k) if (need[k]) {
          unsigned long long v = __hip_atomic_load(&sync[slots[k]],
                                  __ATOMIC_RELAXED, __HIP_MEMORY_SCOPE_AGENT);
          if ((unsigned)(v & 0xFFFu) == tag) { ck[k] = v >> 12; need[k] = false; }
        }
        if (needf) {
          unsigned long long v = __hip_atomic_load(&sync[fslot],
                                  __ATOMIC_RELAXED, __HIP_MEMORY_SCOPE_AGENT);
          if ((unsigned)(v & 0xFFFu) == tag) { flr = v >> 12; needf = false; }
        }
      }
      unsigned long long f = fb;
      f = umax64(f, shfl_u64(flr, 0));
      f = umax64(f, shfl_u64(flr, 1));
      f = umax64(f, shfl_u64(flr, 2));
      // candidate coords (3 per lane)
      float cxx[3], cyy[3], czz[3];
#pragma unroll
      for (int k = 0; k < 3; ++k) {
        int ci = 0x7FFF - (int)(ck[k] & 0x7FFFu);
        cxx[k] = X[3*ci]; cyy[k] = X[3*ci+1]; czz[k] = X[3*ci+2];
      }
      int Jn = 0;
      while (it + Jn < M1 && Jn < 48) {
        unsigned long long mk = umax64(umax64(ck[0], ck[1]), ck[2]);
#pragma unroll
        for (int off = 32; off > 0; off >>= 1) {
          unsigned long long o = shfl_xor_u64(mk, off);
          if (o > mk) mk = o;
        }
        if (!(mk > f)) break;              // outside point could exceed -> exchange
        float px = 0.f, py = 0.f, pz = 0.f;
#pragma unroll
        for (int k = 0; k < 3; ++k) {
          unsigned long long bb = __ballot(ck[k] == mk);
          if (bb) {
            int wl = __ffsll((long long)bb) - 1;
            px = __shfl(cxx[k], wl); py = __shfl(cyy[k], wl); pz = __shfl(czz[k], wl);
            break;
          }
        }
        if (lane == 0) {
          s_pivc[Jn][0] = px; s_pivc[Jn][1] = py; s_pivc[Jn][2] = pz;
          if (sub == 0) cen4a[it + Jn] = make_float4(px, py, pz, 0.f);
        }
#pragma unroll
        for (int k = 0; k < 3; ++k) {
          float d = sqdist(cxx[k], cyy[k], czz[k], px, py, pz);
          float nv = fminf(__uint_as_float((unsigned)(ck[k] >> 15)), d);
          ck[k] = ((unsigned long long)__float_as_uint(nv) << 15) | (ck[k] & 0x7FFFu);
        }
        ++Jn;
      }
      if (lane == 0) s_J = Jn;
    }
    __syncthreads();                       // barrier B
    J = s_J;
    it += J;
    rc += 1;
  }
}

// ---------------------------------------------------------------------------
// Stage-2 FPS, batched picks intra-block (no atomics): 1024 threads,
// 2 pts/thread in registers, pl[] in LDS for candidate coord lookup.
// Per-thread top-3, wave top-3 merge, 32 candidates (16 waves x top-2),
// floor = max wave-3rd; picks exact (same proof as fps1).
// ---------------------------------------------------------------------------
__global__ __launch_bounds__(1024)
void fps2_kernel(const float4* __restrict__ pts, int* __restrict__ ids)
{
  int b = blockIdx.x;
  pts += (size_t)b * M1;
  ids += (size_t)b * SKP;
  int tid = threadIdx.x, lane = tid & 63, wave = tid >> 6;

  __shared__ float4 pl[M1];                 // 32768 B
  __shared__ unsigned long long s_w[16][3];
  __shared__ float s_pivc[16][3];
  __shared__ int s_J;

  float4 f0 = pts[tid], f1 = pts[tid + 1024];
  pl[tid] = f0; pl[tid + 1024] = f1;
  float dist0 = 1e10f, dist1 = 1e10f;
  if (tid == 0) {
    ids[0] = 0;
    s_pivc[0][0] = f0.x; s_pivc[0][1] = f0.y; s_pivc[0][2] = f0.z;
  }
  __syncthreads();

  int it = 1, J = 1;

  while (it < SKP) {
    for (int jp0 = 0; jp0 < J; jp0 += 4) {
      float pxa[4], pya[4], pza[4];
#pragma unroll
      for (int l = 0; l < 4; ++l) {
        int jj = jp0 + l; jj = (jj < J) ? jj : jp0;
        pxa[l] = s_pivc[jj][0]; pya[l] = s_pivc[jj][1]; pza[l] = s_pivc[jj][2];
      }
#pragma unroll
      for (int l = 0; l < 4; ++l) {
        dist0 = fminf(dist0, sqdist(f0.x, f0.y, f0.z, pxa[l], pya[l], pza[l]));
        dist1 = fminf(dist1, sqdist(f1.x, f1.y, f1.z, pxa[l], pya[l], pza[l]));
      }
    }
    unsigned long long k1, k2 = 0, k3 = 0;
    k1 = ((unsigned long long)__float_as_uint(dist0) << 15) | (unsigned)(0x7FFF - tid);
    {
      unsigned long long key =
          ((unsigned long long)__float_as_uint(dist1) << 15) | (unsigned)(0x7FFF - (tid + 1024));
      ins3(k1, k2, k3, key);
    }
#pragma unroll
    for (int off = 32; off > 0; off >>= 1) {
      unsigned long long o1 = shfl_xor_u64(k1, off);
      unsigned long long o2 = shfl_xor_u64(k2, off);
      unsigned long long o3 = shfl_xor_u64(k3, off);
      ins3(k1, k2, k3, o1);
      ins3(k1, k2, k3, o2);
      ins3(k1, k2, k3, o3);
    }
    if (lane == 0) { s_w[wave][0] = k1; s_w[wave][1] = k2; s_w[wave][2] = k3; }
    __syncthreads();                       // barrier A
    if (wave == 0) {
      unsigned long long fb = (lane < 16) ? s_w[lane][2] : 0;
#pragma unroll
      for (int off = 8; off > 0; off >>= 1) {
        unsigned long long o = shfl_xor_u64(fb, off);
        if (o > fb) fb = o;
      }
      unsigned long long f = shfl_u64(fb, 0);
      unsigned long long ck = 0;
      if (lane < 16)      ck = s_w[lane][0];
      else if (lane < 32) ck = s_w[lane - 16][1];
      int ci = (0x7FFF - (int)(ck & 0x7FFFu)) & (M1 - 1);
      float4 c = pl[ci];
      int Jn = 0;
      while (it + Jn < SKP && Jn < 16) {
        unsigned long long mk = ck;
#pragma unroll
        for (int off = 32; off > 0; off >>= 1) {
          unsigned long long o = shfl_xor_u64(mk, off);
          if (o > mk) mk = o;
        }
        if (!(mk > f)) break;
        unsigned long long ball = __ballot(ck == mk);
        int wl = __ffsll((long long)ball) - 1;
        float px = __shfl(c.x, wl), py = __shfl(c.y, wl), pz = __shfl(c.z, wl);
        if (lane == 0) {
          s_pivc[Jn][0] = px; s_pivc[Jn][1] = py; s_pivc[Jn][2] = pz;
          ids[it + Jn] = 0x7FFF - (int)(mk & 0x7FFFu);
        }
        float d = sqdist(c.x, c.y, c.z, px, py, pz);
        float nv = fminf(__uint_as_float((unsigned)(ck >> 15)), d);
        ck = ((unsigned long long)__float_as_uint(nv) << 15) | (ck & 0x7FFFu);
        ++Jn;
      }
      if (lane == 0) s_J = Jn;
    }
    __syncthreads();                       // barrier B
    J = s_J;
    it += J;
  }
}

// ---------------------------------------------------------------------------
// Skeletonization: wave per query, GRAM-form distances.
// Fast path: per-lane sorted top-KL (KL=4 for K=32), heads-merge K rounds
// -> t >= t_true (subset); rescan counts strict-less over ALL points, so
// ctot >= K detects any miss exactly -> rare full-K fallback (~1% of waves).
// S3 path loads 4 consecutive points per lane via 3x float4 (4x fewer VMEM
// insts than 12 scalar loads). Tie-fill = exact lax.top_k semantics.
// ---------------------------------------------------------------------------
template<int K, int KL, int N, bool S3>
__global__ __launch_bounds__(256)
void sklnz_kernel(const float4* __restrict__ queries,
                  const void*   __restrict__ ptsv,
                  float4* __restrict__ outc,
                  float*  __restrict__ outr,
                  int M)
{
  const int CH = N / 64;     // points per lane (S3=false path)
  const int CHP = N / 256;   // packed chunks per lane (S3=true path)
  int wave = threadIdx.x >> 6, lane = threadIdx.x & 63;
  int qid = blockIdx.x * 4 + wave;
  int b = qid / M;
  const float*  P3 = (const float*)ptsv + (size_t)b * N * 3;
  const float4* P4 = (const float4*)ptsv + (size_t)b * N;
  const float4* P4p = (const float4*)P3;   // packed view for S3
  float4 q = queries[qid];
  float q2 = __fadd_rn(__fadd_rn(__fmul_rn(q.x, q.x), __fmul_rn(q.y, q.y)),
                       __fmul_rn(q.z, q.z));

  __shared__ float heads[4][64][K + 1];

  // ---- fast scan: per-lane sorted top-KL ----
  float a[KL];
#pragma unroll
  for (int s = 0; s < KL; ++s) a[s] = 3.0e38f;
  if constexpr (S3) {
    for (int j = 0; j < CHP; ++j) {
      int u = lane + 64 * j;
      float4 A = P4p[3*u], B = P4p[3*u+1], C = P4p[3*u+2];
      float ds[4];
      ds[0] = d2gram(A.x, A.y, A.z, q.x, q.y, q.z, q2);
      ds[1] = d2gram(A.w, B.x, B.y, q.x, q.y, q.z, q2);
      ds[2] = d2gram(B.z, B.w, C.x, q.x, q.y, q.z, q2);
      ds[3] = d2gram(C.y, C.z, C.w, q.x, q.y, q.z, q2);
#pragma unroll
      for (int e = 0; e < 4; ++e) {
#pragma unroll
        for (int s = KL - 1; s > 0; --s) a[s] = fminf(a[s], fmaxf(a[s-1], ds[e]));
        a[0] = fminf(a[0], ds[e]);
      }
    }
  } else {
    for (int j = 0; j < CH; ++j) {
      float4 f = P4[lane + 64 * j];
      float d = d2gram(f.x, f.y, f.z, q.x, q.y, q.z, q2);
#pragma unroll
      for (int s = KL - 1; s > 0; --s) a[s] = fminf(a[s], fmaxf(a[s-1], d));
      a[0] = fminf(a[0], d);
    }
  }
  // ---- merge: K rounds over per-lane lists (sentinel-terminated) ----
#pragma unroll
  for (int s = 0; s < KL; ++s) heads[wave][lane][s] = a[s];
  heads[wave][lane][KL] = 3.1e38f;
  int h = 0; float t = 0.f;
  for (int r = 0; r < K; ++r) {
    float mv = heads[wave][lane][h];
    int   ml = lane;
#pragma unroll
    for (int off = 32; off > 0; off >>= 1) {
      float ov = __shfl_xor(mv, off);
      int   ol = __shfl_xor(ml, off);
      if (ov < mv || (ov == mv && ol < ml)) { mv = ov; ml = ol; }
    }
    t = mv;
    if (ml == lane) h++;
  }

  // ---- rescan: accumulate d < t, count, per-lane first d == t ----
  float sx = 0.f, sy = 0.f, sz = 0.f, sr = 0.f;
  int cl = 0;
  int myNext = 0x7fffffff;
  if constexpr (S3) {
    for (int j = 0; j < CHP; ++j) {
      int u = lane + 64 * j;
      float4 A = P4p[3*u], B = P4p[3*u+1], C = P4p[3*u+2];
      float pxs[4] = {A.x, A.w, B.z, C.y};
      float pys[4] = {A.y, B.x, B.w, C.z};
      float pzs[4] = {A.z, B.y, C.x, C.w};
#pragma unroll
      for (int e = 0; e < 4; ++e) {
        float d = d2gram(pxs[e], pys[e], pzs[e], q.x, q.y, q.z, q2);
        if (d < t) { sx += pxs[e]; sy += pys[e]; sz += pzs[e];
                     sr += sqrtf(fmaxf(d, 0.f)); cl++; }
        else if (d == t && myNext == 0x7fffffff) myNext = 4*u + e;
      }
    }
  } else {
    for (int j = 0; j < CH; ++j) {
      int p = lane + 64 * j;
      float4 f = P4[p];
      float d = d2gram(f.x, f.y, f.z, q.x, q.y, q.z, q2);
      if (d < t) { sx += f.x; sy += f.y; sz += f.z; sr += sqrtf(fmaxf(d, 0.f)); cl++; }
      else if (d == t && myNext == 0x7fffffff) myNext = p;
    }
  }
  int ctot = cl;
#pragma unroll
  for (int off = 32; off > 0; off >>= 1) ctot += __shfl_xor(ctot, off);

  if constexpr (KL < K) {
    if (ctot >= K) {
      // ---- exact fallback: full per-lane top-K (rare, ~1% of waves) ----
      float a2[K];
#pragma unroll
      for (int s = 0; s < K; ++s) a2[s] = 3.0e38f;
      for (int j = 0; j < CHP; ++j) {
        int u = lane + 64 * j;
        float4 A = P4p[3*u], B = P4p[3*u+1], C = P4p[3*u+2];
        float ds[4];
        ds[0] = d2gram(A.x, A.y, A.z, q.x, q.y, q.z, q2);
        ds[1] = d2gram(A.w, B.x, B.y, q.x, q.y, q.z, q2);
        ds[2] = d2gram(B.z, B.w, C.x, q.x, q.y, q.z, q2);
        ds[3] = d2gram(C.y, C.z, C.w, q.x, q.y, q.z, q2);
#pragma unroll
        for (int e = 0; e < 4; ++e) {
#pragma unroll
          for (int s = K - 1; s > 0; --s) a2[s] = fminf(a2[s], fmaxf(a2[s-1], ds[e]));
          a2[0] = fminf(a2[0], ds[e]);
        }
      }
#pragma unroll
      for (int s = 0; s < K; ++s) heads[wave][lane][s] = a2[s];
      heads[wave][lane][K] = 3.1e38f;
      h = 0;
      for (int r = 0; r < K; ++r) {
        float mv = heads[wave][lane][h];
        int   ml = lane;
#pragma unroll
        for (int off = 32; off > 0; off >>= 1) {
          float ov = __shfl_xor(mv, off);
          int   ol = __shfl_xor(ml, off);
          if (ov < mv || (ov == mv && ol < ml)) { mv = ov; ml = ol; }
        }
        t = mv;
        if (ml == lane) h++;
      }
      sx = sy = sz = sr = 0.f; cl = 0; myNext = 0x7fffffff;
      for (int j = 0; j < CHP; ++j) {
        int u = lane + 64 * j;
        float4 A = P4p[3*u], B = P4p[3*u+1], C = P4p[3*u+2];
        float pxs[4] = {A.x, A.w, B.z, C.y};
        float pys[4] = {A.y, B.x, B.w, C.z};
        float pzs[4] = {A.z, B.y, C.x, C.w};
#pragma unroll
        for (int e = 0; e < 4; ++e) {
          float d = d2gram(pxs[e], pys[e], pzs[e], q.x, q.y, q.z, q2);
          if (d < t) { sx += pxs[e]; sy += pys[e]; sz += pzs[e];
                       sr += sqrtf(fmaxf(d, 0.f)); cl++; }
          else if (d == t && myNext == 0x7fffffff) myNext = 4*u + e;
        }
      }
      ctot = cl;
#pragma unroll
      for (int off = 32; off > 0; off >>= 1) ctot += __shfl_xor(ctot, off);
    }
  }

  int need = K - ctot;               // >= 1, <= multiplicity of t
  float rt = sqrtf(fmaxf(t, 0.f));

  for (int e0 = 0; e0 < need; ++e0) {
    int mn = myNext;
#pragma unroll
    for (int off = 32; off > 0; off >>= 1) mn = min(mn, __shfl_xor(mn, off));
    if (myNext == mn) {              // unique owner (index sets disjoint)
      float px, py, pz;
      if (S3) { px = P3[3*mn]; py = P3[3*mn+1]; pz = P3[3*mn+2]; }
      else    { float4 f = P4[mn]; px = f.x; py = f.y; pz = f.z; }
      sx += px; sy += py; sz += pz; sr += rt;
      int nx = 0x7fffffff;
      if constexpr (S3) {
        for (int j = ((mn >> 2) - lane) / 64; j < CHP && nx == 0x7fffffff; ++j) {
          int u = lane + 64 * j;
          float4 A = P4p[3*u], B = P4p[3*u+1], C = P4p[3*u+2];
          float pxs[4] = {A.x, A.w, B.z, C.y};
          float pys[4] = {A.y, B.x, B.w, C.z};
          float pzs[4] = {A.z, B.y, C.x, C.w};
#pragma unroll
          for (int e = 0; e < 4; ++e) {
            int p = 4*u + e;
            float d = d2gram(pxs[e], pys[e], pzs[e], q.x, q.y, q.z, q2);
            if (p > mn && d == t && nx == 0x7fffffff) nx = p;
          }
        }
      } else {
        for (int j = (mn - lane) / 64 + 1; j < CH && nx == 0x7fffffff; ++j) {
          int p = lane + 64 * j;
          float4 f = P4[p];
          float d = d2gram(f.x, f.y, f.z, q.x, q.y, q.z, q2);
          if (d == t) nx = p;
        }
      }
      myNext = nx;
    }
  }

#pragma unroll
  for (int off = 32; off > 0; off >>= 1) {
    sx += __shfl_xor(sx, off);
    sy += __shfl_xor(sy, off);
    sz += __shfl_xor(sz, off);
    sr += __shfl_xor(sr, off);
  }
  if (lane == 0) {
    const float inv = 1.0f / (float)K;
    outc[qid] = make_float4(sx * inv, sy * inv, sz * inv, 0.f);
    outr[qid] = sr * inv;
  }
}

// ---------------------------------------------------------------------------
__global__ void gather2_kernel(const float4* __restrict__ cen4,
                               const float* __restrict__ rad1,
                               const int* __restrict__ ids2,
                               float4* __restrict__ cen2,
                               float* __restrict__ radg)
{
  int g = blockIdx.x * 256 + threadIdx.x;
  if (g >= BATCH * SKP) return;
  int b = g / SKP;
  int p = ids2[g];
  cen2[g] = cen4[(size_t)b * M1 + p];
  radg[g] = rad1[(size_t)b * M1 + p];
}

__global__ void finalize_kernel(const float4* __restrict__ cen,
                                const float* __restrict__ radg,
                                const float* __restrict__ rad2,
                                const float* __restrict__ tmpl,
                                float* __restrict__ out)
{
  int g = blockIdx.x * 256 + threadIdx.x;
  int s = g >> 7;
  int j = g & 127;
  float4 c = cen[s];
  float r = __fmul_rn(__fadd_rn(radg[s], rad2[s]), 1.5f);
  float tx = tmpl[3*j], ty = tmpl[3*j+1], tz = tmpl[3*j+2];
  float* sp = out + BATCH * SKP * 3;
  sp[3*g]     = __fadd_rn(c.x, __fmul_rn(r, tx));
  sp[3*g + 1] = __fadd_rn(c.y, __fmul_rn(r, ty));
  sp[3*g + 2] = __fadd_rn(c.z, __fmul_rn(r, tz));
  if (j == 0) {
    out[3*s] = c.x; out[3*s+1] = c.y; out[3*s+2] = c.z;
    out[BATCH*SKP*3 + BATCH*SKP*SPHN*3 + s] = r;
  }
}

// ---------------------------------------------------------------------------
extern "C" void kernel_launch(void* const* d_in, const int* in_sizes, int n_in,
                              void* d_out, int out_size, void* d_ws, size_t ws_size,
                              hipStream_t stream)
{
  const float* xyz  = (const float*)d_in[0];   // f32 [B, N, 3]
  const float* tmpl = (const float*)d_in[1];   // f32 [128, 3]
  float* out = (float*)d_out;                  // f32 outputs
  char* ws = (char*)d_ws;

  // total ws footprint: 432,128 B
  float4* cen4a = (float4*)(ws + 32768);    // 131072 B
  float4* cen4b = (float4*)(ws + 163840);   // 131072 B
  float*  rad1  = (float*) (ws + 294912);   //  32768 B
  int*    ids2  = (int*)   (ws + 327680);   //   8192 B
  float4* cen2a = (float4*)(ws + 335872);   //  32768 B
  float4* cen2b = (float4*)(ws + 368640);   //  32768 B
  float*  radg  = (float*) (ws + 401408);   //   8192 B
  float*  rad2  = (float*) (ws + 409600);   //   8192 B
  unsigned long long* sync = (unsigned long long*)(ws + 417792); // 14336 B

  // Stage 1: batched-candidate exact FPS (4 blocks/batch, depth-3),
  // writes cen4a directly (gather1 fused away)
  fps1_kernel<<<BATCH * 4, 1024, 0, stream>>>(xyz, cen4a, sync);
  // two skeletonization passes, k=32 (fast per-lane top-4 + exact fallback)
  sklnz_kernel<KA, 4, NPTS, true><<<BATCH * M1 / 4, 256, 0, stream>>>(cen4a, xyz, cen4b, rad1, M1);
  sklnz_kernel<KA, 4, NPTS, true><<<BATCH * M1 / 4, 256, 0, stream>>>(cen4b, xyz, cen4a, rad1, M1);
  // Stage 2: batched-pick FPS 2048 -> 512 (1 block/batch, intra-block)
  fps2_kernel<<<BATCH, 1024, 0, stream>>>(cen4a, ids2);
  gather2_kernel<<<(BATCH * SKP + 255) / 256, 256, 0, stream>>>(cen4a, rad1, ids2, cen2a, radg);
  // two skeletonization passes, k=2 (KL == K -> exact, no fallback)
  sklnz_kernel<KB, KB, M1, false><<<BATCH * SKP / 4, 256, 0, stream>>>(cen2a, cen4a, cen2b, rad2, SKP);
  sklnz_kernel<KB, KB, M1, false><<<BATCH * SKP / 4, 256, 0, stream>>>(cen2b, cen4a, cen2a, rad2, SKP);
  // Outputs: centers, sphere points, radii (f32)
  finalize_kernel<<<BATCH * SKP * SPHN / 256, 256, 0, stream>>>(cen2a, radg, rad2, tmpl, out);
}